// Round 2
// baseline (743.183 us; speedup 1.0000x reference)
//
#include <hip/hip_runtime.h>

typedef _Float16 half8 __attribute__((ext_vector_type(8)));
typedef _Float16 half4 __attribute__((ext_vector_type(4)));
typedef _Float16 half2t __attribute__((ext_vector_type(2)));
typedef float f32x4 __attribute__((ext_vector_type(4)));
typedef float f32x2 __attribute__((ext_vector_type(2)));

#define NHEAD 16
#define SEQ 512
#define DIM 128
#define HID 2048
#define SCACHE 8192
#define CAP 64
#define SCALE 0.08838834764831845f   // 1/sqrt(128)
#define NEG_INF (-__builtin_inff())

// ---------------------------------------------------------------------------
// Generic C[M,N] = A[M,K] @ B[N,K]^T   (fp32 in/out, f16 MFMA, fp32 accum)
// Used for QKV (k/v precision non-critical; q smooth uses) and out-proj.
// ---------------------------------------------------------------------------
__global__ __launch_bounds__(256) void gemm_xwT(const float* __restrict__ A,
                                                const float* __restrict__ B,
                                                float* __restrict__ C,
                                                int M, int N, int K, int gridN) {
  __shared__ __align__(16) _Float16 As[128][88];
  __shared__ __align__(16) _Float16 Bs[128][88];
  int b = blockIdx.x;
  int nblk = b % gridN, mblk = b / gridN;
  int t = threadIdx.x;
  int lane = t & 63, wid = t >> 6;
  int wm = (wid >> 1) * 64, wn = (wid & 1) * 64;
  f32x4 acc[4][4] = {};
  const float* Ab = A + (size_t)mblk * 128 * K;
  const float* Bb = B + (size_t)nblk * 128 * K;
  int rowS = t >> 4, c4 = (t & 15) * 4;

  for (int k0 = 0; k0 < K; k0 += 64) {
#pragma unroll
    for (int i = 0; i < 8; ++i) {
      int row = rowS + 16 * i;
      float4 av = *(const float4*)(Ab + (size_t)row * K + k0 + c4);
      float4 bv = *(const float4*)(Bb + (size_t)row * K + k0 + c4);
      half4 ah = {(_Float16)av.x, (_Float16)av.y, (_Float16)av.z, (_Float16)av.w};
      half4 bh = {(_Float16)bv.x, (_Float16)bv.y, (_Float16)bv.z, (_Float16)bv.w};
      *(half4*)&As[row][c4] = ah;
      *(half4*)&Bs[row][c4] = bh;
    }
    __syncthreads();
#pragma unroll
    for (int ks = 0; ks < 2; ++ks) {
      int ko = ks * 32 + (lane >> 4) * 8;
      int rr = lane & 15;
      half8 af[4], bf[4];
#pragma unroll
      for (int i = 0; i < 4; ++i) af[i] = *(const half8*)&As[wm + i * 16 + rr][ko];
#pragma unroll
      for (int j = 0; j < 4; ++j) bf[j] = *(const half8*)&Bs[wn + j * 16 + rr][ko];
#pragma unroll
      for (int i = 0; i < 4; ++i)
#pragma unroll
        for (int j = 0; j < 4; ++j)
          acc[i][j] = __builtin_amdgcn_mfma_f32_16x16x32_f16(af[i], bf[j], acc[i][j], 0, 0, 0);
    }
    __syncthreads();
  }
  int cR = (lane >> 4) * 4, cC = lane & 15;
#pragma unroll
  for (int i = 0; i < 4; ++i)
#pragma unroll
    for (int j = 0; j < 4; ++j) {
      int row = mblk * 128 + wm + i * 16 + cR;
      int col = nblk * 128 + wn + j * 16 + cC;
#pragma unroll
      for (int r = 0; r < 4; ++r)
        C[(size_t)(row + r) * N + col] = acc[i][j][r];
    }
}

// ---------------------------------------------------------------------------
// q-third of QKV at fp32 accuracy via 3-term f16 split MFMA:
//   q = x_hi*W_hi + x_hi*W_lo + x_lo*W_hi    (rel err ~3e-7)
// M=512, N=2048 (Wqkv rows 0..2047), K=2048, BK=32. Output qhi[s][h*128+d].
// ---------------------------------------------------------------------------
__global__ __launch_bounds__(256) void gemm_q_hi(const float* __restrict__ A,
                                                 const float* __restrict__ B,
                                                 float* __restrict__ C) {
  __shared__ __align__(16) _Float16 Ah[128][40], Al[128][40];
  __shared__ __align__(16) _Float16 Bh[128][40], Bl[128][40];
  int b = blockIdx.x;
  int nblk = b & 15, mblk = b >> 4;
  int t = threadIdx.x, lane = t & 63, wid = t >> 6;
  int wm = (wid >> 1) * 64, wn = (wid & 1) * 64;
  f32x4 acc[4][4] = {};
  const float* Ab = A + (size_t)mblk * 128 * 2048;
  const float* Bb = B + (size_t)nblk * 128 * 2048;

  for (int k0 = 0; k0 < 2048; k0 += 32) {
#pragma unroll
    for (int i = 0; i < 4; ++i) {
      int f = t + 256 * i;
      int row = f >> 3, c = (f & 7) * 4;
      float4 av = *(const float4*)(Ab + (size_t)row * 2048 + k0 + c);
      float4 bv = *(const float4*)(Bb + (size_t)row * 2048 + k0 + c);
      half4 ah = {(_Float16)av.x, (_Float16)av.y, (_Float16)av.z, (_Float16)av.w};
      half4 bh = {(_Float16)bv.x, (_Float16)bv.y, (_Float16)bv.z, (_Float16)bv.w};
      half4 al = {(_Float16)(av.x - (float)ah.x), (_Float16)(av.y - (float)ah.y),
                  (_Float16)(av.z - (float)ah.z), (_Float16)(av.w - (float)ah.w)};
      half4 bl = {(_Float16)(bv.x - (float)bh.x), (_Float16)(bv.y - (float)bh.y),
                  (_Float16)(bv.z - (float)bh.z), (_Float16)(bv.w - (float)bh.w)};
      *(half4*)&Ah[row][c] = ah;
      *(half4*)&Al[row][c] = al;
      *(half4*)&Bh[row][c] = bh;
      *(half4*)&Bl[row][c] = bl;
    }
    __syncthreads();
    int ko = (lane >> 4) * 8, rr = lane & 15;
    half8 afh[4], afl[4], bfh[4], bfl[4];
#pragma unroll
    for (int i = 0; i < 4; ++i) {
      afh[i] = *(const half8*)&Ah[wm + i * 16 + rr][ko];
      afl[i] = *(const half8*)&Al[wm + i * 16 + rr][ko];
      bfh[i] = *(const half8*)&Bh[wn + i * 16 + rr][ko];
      bfl[i] = *(const half8*)&Bl[wn + i * 16 + rr][ko];
    }
#pragma unroll
    for (int i = 0; i < 4; ++i)
#pragma unroll
      for (int j = 0; j < 4; ++j) {
        acc[i][j] = __builtin_amdgcn_mfma_f32_16x16x32_f16(afl[i], bfh[j], acc[i][j], 0, 0, 0);
        acc[i][j] = __builtin_amdgcn_mfma_f32_16x16x32_f16(afh[i], bfl[j], acc[i][j], 0, 0, 0);
        acc[i][j] = __builtin_amdgcn_mfma_f32_16x16x32_f16(afh[i], bfh[j], acc[i][j], 0, 0, 0);
      }
    __syncthreads();
  }
  int cR = (lane >> 4) * 4, cC = lane & 15;
#pragma unroll
  for (int i = 0; i < 4; ++i)
#pragma unroll
    for (int j = 0; j < 4; ++j) {
      int row = mblk * 128 + wm + i * 16 + cR;
      int col = nblk * 128 + wn + j * 16 + cC;
#pragma unroll
      for (int r = 0; r < 4; ++r)
        C[(size_t)(row + r) * 2048 + col] = acc[i][j][r];
    }
}

// ---------------------------------------------------------------------------
// k_cache f16 normalized copy for the candidate filter. One wave per row.
// ---------------------------------------------------------------------------
__global__ __launch_bounds__(256) void cache_norm(const float* __restrict__ kc,
                                                  _Float16* __restrict__ kn16) {
  int w = threadIdx.x >> 6, lane = threadIdx.x & 63;
  int row = blockIdx.x * 4 + w;
  f32x2 v = *(const f32x2*)(kc + (size_t)row * DIM + lane * 2);
  float s = v[0] * v[0] + v[1] * v[1];
#pragma unroll
  for (int off = 32; off; off >>= 1) s += __shfl_xor(s, off);
  float inv = rsqrtf(s);
  half2t o = {(_Float16)(v[0] * inv), (_Float16)(v[1] * inv)};
  *(half2t*)(kn16 + (size_t)row * DIM + lane * 2) = o;
}

// ---------------------------------------------------------------------------
// From qkv: per-head f16 q, k_local, normalized q. Wave per (h,s).
// ---------------------------------------------------------------------------
__global__ __launch_bounds__(256) void prep_local(const float* __restrict__ qkv,
                                                  _Float16* __restrict__ q16,
                                                  _Float16* __restrict__ k16,
                                                  _Float16* __restrict__ qn16) {
  int w = threadIdx.x >> 6, lane = threadIdx.x & 63;
  int rid = blockIdx.x * 4 + w;
  int h = rid >> 9, s = rid & 511;
  const float* qp = qkv + (size_t)s * (3 * HID) + h * DIM + lane * 2;
  f32x2 q = *(const f32x2*)qp;
  f32x2 k = *(const f32x2*)(qp + HID);
  float ss = q[0] * q[0] + q[1] * q[1];
#pragma unroll
  for (int off = 32; off; off >>= 1) ss += __shfl_xor(ss, off);
  float inv = rsqrtf(ss);
  half2t qh = {(_Float16)q[0], (_Float16)q[1]};
  half2t kh = {(_Float16)k[0], (_Float16)k[1]};
  half2t qnh = {(_Float16)(q[0] * inv), (_Float16)(q[1] * inv)};
  *(half2t*)(q16 + (size_t)rid * DIM + lane * 2) = qh;
  *(half2t*)(k16 + (size_t)rid * DIM + lane * 2) = kh;
  *(half2t*)(qn16 + (size_t)rid * DIM + lane * 2) = qnh;
}

// ---------------------------------------------------------------------------
// Candidate filter: sim = Qn @ Kn^T per head via f16 MFMA; threshold 0.249
// (margin 1e-3 >> f16 error ~7e-5). Appends candidates via global atomics.
// Decisions are NOT made here — select_topk re-scores in double.
// ---------------------------------------------------------------------------
__global__ __launch_bounds__(256) void sim_cand(const _Float16* __restrict__ qn16,
                                                const _Float16* __restrict__ kn16,
                                                int* __restrict__ cnt,
                                                int* __restrict__ cidx) {
  __shared__ __align__(16) _Float16 Ks[128][136];
  __shared__ __align__(16) _Float16 Qs[64][136];
  int b = blockIdx.x;
  int h = b & 15, cblk = b >> 4;
  int t = threadIdx.x, lane = t & 63, w = t >> 6;

  const _Float16* kb = kn16 + ((size_t)(h * SCACHE + cblk * 128)) * DIM;
#pragma unroll
  for (int i = 0; i < 8; ++i) {
    int f = t + 256 * i;
    int row = f >> 4, c8 = (f & 15) * 8;
    *(uint4*)&Ks[row][c8] = *(const uint4*)(kb + (size_t)row * DIM + c8);
  }

  for (int qt = 0; qt < 8; ++qt) {
    __syncthreads();
    const _Float16* qb = qn16 + ((size_t)(h * SEQ + qt * 64)) * DIM;
#pragma unroll
    for (int i = 0; i < 4; ++i) {
      int f = t + 256 * i;
      int row = f >> 4, c8 = (f & 15) * 8;
      *(uint4*)&Qs[row][c8] = *(const uint4*)(qb + (size_t)row * DIM + c8);
    }
    __syncthreads();

    f32x4 acc[4][2] = {};
#pragma unroll
    for (int ks = 0; ks < 4; ++ks) {
      int ko = ks * 32 + (lane >> 4) * 8;
      int rr = lane & 15;
      half8 af[4], bf[2];
#pragma unroll
      for (int i = 0; i < 4; ++i) af[i] = *(const half8*)&Qs[i * 16 + rr][ko];
#pragma unroll
      for (int j = 0; j < 2; ++j) bf[j] = *(const half8*)&Ks[w * 32 + j * 16 + rr][ko];
#pragma unroll
      for (int i = 0; i < 4; ++i)
#pragma unroll
        for (int j = 0; j < 2; ++j)
          acc[i][j] = __builtin_amdgcn_mfma_f32_16x16x32_f16(af[i], bf[j], acc[i][j], 0, 0, 0);
    }
    int qrow_base = qt * 64 + ((lane >> 4) << 2);
    int key_base = cblk * 128 + w * 32 + (lane & 15);
#pragma unroll
    for (int i = 0; i < 4; ++i)
#pragma unroll
      for (int j = 0; j < 2; ++j)
#pragma unroll
        for (int r = 0; r < 4; ++r) {
          float v = acc[i][j][r];
          if (v > 0.249f) {
            int q = qrow_base + i * 16 + r;
            int rowid = h * SEQ + q;
            int pos = atomicAdd(&cnt[rowid], 1);
            if (pos < CAP) cidx[rowid * CAP + pos] = key_base + j * 16;
          }
        }
  }
}

// ---------------------------------------------------------------------------
// Per (h,q) row: re-score candidates in DOUBLE from fp32-accurate qhi,
// top-16 with jax tie-break (value desc, index asc), threshold 0.25 exact.
// ---------------------------------------------------------------------------
__global__ __launch_bounds__(256) void select_topk(const int* __restrict__ cnt,
                                                   const int* __restrict__ cidx,
                                                   const float* __restrict__ qhi,
                                                   const float* __restrict__ kcache,
                                                   int* __restrict__ sel_idx,
                                                   float* __restrict__ sel_score) {
  int w = threadIdx.x >> 6, lane = threadIdx.x & 63;
  int rowid = blockIdx.x * 4 + w;
  int h = rowid >> 9, s = rowid & 511;
  const float* qp = qhi + (size_t)s * HID + h * DIM + lane * 2;
  double qx = qp[0], qy = qp[1];
  double qs = qx * qx + qy * qy;
#pragma unroll
  for (int off = 32; off; off >>= 1) qs += __shfl_xor(qs, off);
  double qn = sqrt(qs);
  int n = min(cnt[rowid], CAP);
  double tv[16];
  float td[16];
  int ti[16];
#pragma unroll
  for (int k = 0; k < 16; ++k) { tv[k] = -1e300; td[k] = 0.f; ti[k] = 0x7fffffff; }

  for (int c = 0; c < n; ++c) {
    int idx = cidx[rowid * CAP + c];
    const float* kp = kcache + ((size_t)(h * SCACHE + idx)) * DIM + lane * 2;
    double kx = kp[0], ky = kp[1];
    double d = qx * kx + qy * ky;
    double ks = kx * kx + ky * ky;
#pragma unroll
    for (int off = 32; off; off >>= 1) {
      d += __shfl_xor(d, off);
      ks += __shfl_xor(ks, off);
    }
    double sim = d / (qn * sqrt(ks));
    double v = sim;
    float vd = (float)(d * (double)SCALE);
    int vi = idx;
#pragma unroll
    for (int k = 0; k < 16; ++k) {
      bool better = (v > tv[k]) || (v == tv[k] && vi < ti[k]);
      if (better) {
        double t0 = tv[k]; float t2 = td[k]; int t1 = ti[k];
        tv[k] = v; td[k] = vd; ti[k] = vi;
        v = t0; vd = t2; vi = t1;
      }
    }
  }
  if (lane == 0) {
#pragma unroll
    for (int k = 0; k < 16; ++k) {
      bool valid = tv[k] > 0.25;
      sel_idx[rowid * 16 + k] = valid ? ti[k] : 0;
      sel_score[rowid * 16 + k] = valid ? td[k] : NEG_INF;
    }
  }
}

// ---------------------------------------------------------------------------
// Attention: one block per (h, 16-query tile). Local scores via f16 MFMA,
// fp32 softmax over 544 slots, fp32 vector PV, writes ctx[s][h*128+d].
// ---------------------------------------------------------------------------
__global__ __launch_bounds__(256) void attn(const float* __restrict__ qkv,
                                            const _Float16* __restrict__ q16,
                                            const _Float16* __restrict__ k16,
                                            const float* __restrict__ bias,
                                            const int* __restrict__ sel_idx,
                                            const float* __restrict__ sel_score,
                                            const float* __restrict__ vcache,
                                            float* __restrict__ ctx) {
  __shared__ __align__(16) float sc[16][560];
  __shared__ float invd[16];
  int b = blockIdx.x;
  int h = b & 15, qb = b >> 4;
  int q0 = qb * 16;
  int t = threadIdx.x, lane = t & 63, w = t >> 6;

  for (int i = t; i < 16 * 560; i += 256) (&sc[0][0])[i] = NEG_INF;
  __syncthreads();

  const _Float16* qbp = q16 + ((size_t)(h * SEQ + q0)) * DIM;
  half8 af[4];
#pragma unroll
  for (int ks = 0; ks < 4; ++ks)
    af[ks] = *(const half8*)(qbp + (size_t)(lane & 15) * DIM + ks * 32 + (lane >> 4) * 8);
  int nk = q0 + 16;
  for (int kt = 0; kt < nk; kt += 64) {
    int kb = kt + w * 16;
    if (kb < nk) {
      const _Float16* kp = k16 + ((size_t)(h * SEQ + kb)) * DIM;
      f32x4 acc = {};
#pragma unroll
      for (int ks = 0; ks < 4; ++ks) {
        half8 bf = *(const half8*)(kp + (size_t)(lane & 15) * DIM + ks * 32 + (lane >> 4) * 8);
        acc = __builtin_amdgcn_mfma_f32_16x16x32_f16(af[ks], bf, acc, 0, 0, 0);
      }
      int key = kb + (lane & 15);
      int r0 = (lane >> 4) * 4;
#pragma unroll
      for (int r = 0; r < 4; ++r) {
        int qrow = q0 + r0 + r;
        float sv = (key <= qrow)
                       ? acc[r] * SCALE + bias[((size_t)h * SEQ + qrow) * SEQ + key]
                       : NEG_INF;
        sc[r0 + r][key] = sv;
      }
    }
  }
  {
    int r = t >> 4, j = t & 15;
    int rowid = h * SEQ + q0 + r;
    sc[r][512 + j] = sel_score[rowid * 16 + j];
  }
  __syncthreads();

  for (int r = w * 4; r < w * 4 + 4; ++r) {
    float m = NEG_INF;
    for (int j = lane; j < 544; j += 64) m = fmaxf(m, sc[r][j]);
#pragma unroll
    for (int off = 32; off; off >>= 1) m = fmaxf(m, __shfl_xor(m, off));
    float sum = 0.f;
    for (int j = lane; j < 544; j += 64) {
      float e = __expf(sc[r][j] - m);
      sc[r][j] = e;
      sum += e;
    }
#pragma unroll
    for (int off = 32; off; off >>= 1) sum += __shfl_xor(sum, off);
    if (lane == 0) invd[r] = 1.f / sum;
  }
  __syncthreads();

  int d4 = (t & 31) * 4;
  int r0 = (t >> 5) * 2;
  f32x4 a0 = {}, a1 = {};
  const float* vb = qkv + 2 * HID + h * DIM + d4;
  for (int j4 = 0; j4 < nk; j4 += 4) {
    f32x4 w0 = *(const f32x4*)&sc[r0][j4];
    f32x4 w1 = *(const f32x4*)&sc[r0 + 1][j4];
#pragma unroll
    for (int jj = 0; jj < 4; ++jj) {
      f32x4 v = *(const f32x4*)(vb + (size_t)(j4 + jj) * (3 * HID));
      a0 += v * w0[jj];
      a1 += v * w1[jj];
    }
  }
  for (int rr = 0; rr < 2; ++rr) {
    int r = r0 + rr;
    int rowid = h * SEQ + q0 + r;
#pragma unroll
    for (int j = 0; j < 16; ++j) {
      float wv = sc[r][512 + j];
      if (wv > 0.f) {
        int idx = sel_idx[rowid * 16 + j];
        f32x4 v = *(const f32x4*)(vcache + ((size_t)(h * SCACHE + idx)) * DIM + d4);
        if (rr == 0) a0 += v * wv; else a1 += v * wv;
      }
    }
  }
  f32x4 o0 = a0 * invd[r0], o1 = a1 * invd[r0 + 1];
  *(f32x4*)(ctx + (size_t)(q0 + r0) * HID + h * DIM + d4) = o0;
  *(f32x4*)(ctx + (size_t)(q0 + r0 + 1) * HID + h * DIM + d4) = o1;
}

// ---------------------------------------------------------------------------
extern "C" void kernel_launch(void* const* d_in, const int* in_sizes, int n_in,
                              void* d_out, int out_size, void* d_ws, size_t ws_size,
                              hipStream_t stream) {
  const float* hidden = (const float*)d_in[0];
  const float* Wqkv   = (const float*)d_in[1];
  const float* Wout   = (const float*)d_in[2];
  const float* kcache = (const float*)d_in[3];
  const float* vcache = (const float*)d_in[4];
  const float* bias   = (const float*)d_in[5];

  char* ws = (char*)d_ws;
  size_t off = 0;
  float*    qkv   = (float*)(ws + off);    off += (size_t)SEQ * 3 * HID * 4;
  float*    qhi   = (float*)(ws + off);    off += (size_t)SEQ * HID * 4;
  _Float16* q16   = (_Float16*)(ws + off); off += (size_t)NHEAD * SEQ * DIM * 2;
  _Float16* k16   = (_Float16*)(ws + off); off += (size_t)NHEAD * SEQ * DIM * 2;
  _Float16* qn16  = (_Float16*)(ws + off); off += (size_t)NHEAD * SEQ * DIM * 2;
  _Float16* kn16  = (_Float16*)(ws + off); off += (size_t)NHEAD * SCACHE * DIM * 2;
  int*      ccnt  = (int*)(ws + off);      off += (size_t)NHEAD * SEQ * 4;
  int*      cidx  = (int*)(ws + off);      off += (size_t)NHEAD * SEQ * CAP * 4;
  int*      selidx  = (int*)(ws + off);    off += (size_t)NHEAD * SEQ * 16 * 4;
  float*    selsc   = (float*)(ws + off);  off += (size_t)NHEAD * SEQ * 16 * 4;
  float*    ctx   = (float*)(ws + off);    off += (size_t)SEQ * HID * 4;

  hipMemsetAsync(ccnt, 0, (size_t)NHEAD * SEQ * 4, stream);
  cache_norm<<<dim3(NHEAD * SCACHE / 4), dim3(256), 0, stream>>>(kcache, kn16);
  gemm_xwT<<<dim3(4 * 48), dim3(256), 0, stream>>>(hidden, Wqkv, qkv, 512, 6144, 2048, 48);
  gemm_q_hi<<<dim3(4 * 16), dim3(256), 0, stream>>>(hidden, Wqkv, qhi);
  prep_local<<<dim3(NHEAD * SEQ / 4), dim3(256), 0, stream>>>(qkv, q16, k16, qn16);
  sim_cand<<<dim3(NHEAD * 64), dim3(256), 0, stream>>>(qn16, kn16, ccnt, cidx);
  select_topk<<<dim3(NHEAD * SEQ / 4), dim3(256), 0, stream>>>(ccnt, cidx, qhi, kcache,
                                                               selidx, selsc);
  attn<<<dim3(NHEAD * 32), dim3(256), 0, stream>>>(qkv, q16, k16, bias, selidx, selsc,
                                                   vcache, ctx);
  gemm_xwT<<<dim3(4 * 16), dim3(256), 0, stream>>>(ctx, Wout, (float*)d_out, 512, 2048, 2048, 16);
}

// Round 3
// 618.750 us; speedup vs baseline: 1.2011x; 1.2011x over previous
//
#include <hip/hip_runtime.h>

typedef _Float16 half8 __attribute__((ext_vector_type(8)));
typedef _Float16 half4 __attribute__((ext_vector_type(4)));
typedef _Float16 half2t __attribute__((ext_vector_type(2)));
typedef float f32x4 __attribute__((ext_vector_type(4)));
typedef float f32x2 __attribute__((ext_vector_type(2)));

#define NHEAD 16
#define SEQ 512
#define DIM 128
#define HID 2048
#define SCACHE 8192
#define CAP 64
#define SCALE 0.08838834764831845f   // 1/sqrt(128)
#define NEG_INF (-__builtin_inff())

// ---------------------------------------------------------------------------
// Generic C[M,N] = A[M,K] @ B[N,K]^T   (fp32 in/out, f16 MFMA, fp32 accum)
// ---------------------------------------------------------------------------
__global__ __launch_bounds__(256) void gemm_xwT(const float* __restrict__ A,
                                                const float* __restrict__ B,
                                                float* __restrict__ C,
                                                int M, int N, int K, int gridN) {
  __shared__ __align__(16) _Float16 As[128][88];
  __shared__ __align__(16) _Float16 Bs[128][88];
  int b = blockIdx.x;
  int nblk = b % gridN, mblk = b / gridN;
  int t = threadIdx.x;
  int lane = t & 63, wid = t >> 6;
  int wm = (wid >> 1) * 64, wn = (wid & 1) * 64;
  f32x4 acc[4][4] = {};
  const float* Ab = A + (size_t)mblk * 128 * K;
  const float* Bb = B + (size_t)nblk * 128 * K;
  int rowS = t >> 4, c4 = (t & 15) * 4;

  for (int k0 = 0; k0 < K; k0 += 64) {
#pragma unroll
    for (int i = 0; i < 8; ++i) {
      int row = rowS + 16 * i;
      float4 av = *(const float4*)(Ab + (size_t)row * K + k0 + c4);
      float4 bv = *(const float4*)(Bb + (size_t)row * K + k0 + c4);
      half4 ah = {(_Float16)av.x, (_Float16)av.y, (_Float16)av.z, (_Float16)av.w};
      half4 bh = {(_Float16)bv.x, (_Float16)bv.y, (_Float16)bv.z, (_Float16)bv.w};
      *(half4*)&As[row][c4] = ah;
      *(half4*)&Bs[row][c4] = bh;
    }
    __syncthreads();
#pragma unroll
    for (int ks = 0; ks < 2; ++ks) {
      int ko = ks * 32 + (lane >> 4) * 8;
      int rr = lane & 15;
      half8 af[4], bf[4];
#pragma unroll
      for (int i = 0; i < 4; ++i) af[i] = *(const half8*)&As[wm + i * 16 + rr][ko];
#pragma unroll
      for (int j = 0; j < 4; ++j) bf[j] = *(const half8*)&Bs[wn + j * 16 + rr][ko];
#pragma unroll
      for (int i = 0; i < 4; ++i)
#pragma unroll
        for (int j = 0; j < 4; ++j)
          acc[i][j] = __builtin_amdgcn_mfma_f32_16x16x32_f16(af[i], bf[j], acc[i][j], 0, 0, 0);
    }
    __syncthreads();
  }
  int cR = (lane >> 4) * 4, cC = lane & 15;
#pragma unroll
  for (int i = 0; i < 4; ++i)
#pragma unroll
    for (int j = 0; j < 4; ++j) {
      int row = mblk * 128 + wm + i * 16 + cR;
      int col = nblk * 128 + wn + j * 16 + cC;
#pragma unroll
      for (int r = 0; r < 4; ++r)
        C[(size_t)(row + r) * N + col] = acc[i][j][r];
    }
}

// ---------------------------------------------------------------------------
// q-third of QKV at fp32 accuracy via 3-term f16 split MFMA.
// ---------------------------------------------------------------------------
__global__ __launch_bounds__(256) void gemm_q_hi(const float* __restrict__ A,
                                                 const float* __restrict__ B,
                                                 float* __restrict__ C) {
  __shared__ __align__(16) _Float16 Ah[128][40], Al[128][40];
  __shared__ __align__(16) _Float16 Bh[128][40], Bl[128][40];
  int b = blockIdx.x;
  int nblk = b & 15, mblk = b >> 4;
  int t = threadIdx.x, lane = t & 63, wid = t >> 6;
  int wm = (wid >> 1) * 64, wn = (wid & 1) * 64;
  f32x4 acc[4][4] = {};
  const float* Ab = A + (size_t)mblk * 128 * 2048;
  const float* Bb = B + (size_t)nblk * 128 * 2048;

  for (int k0 = 0; k0 < 2048; k0 += 32) {
#pragma unroll
    for (int i = 0; i < 4; ++i) {
      int f = t + 256 * i;
      int row = f >> 3, c = (f & 7) * 4;
      float4 av = *(const float4*)(Ab + (size_t)row * 2048 + k0 + c);
      float4 bv = *(const float4*)(Bb + (size_t)row * 2048 + k0 + c);
      half4 ah = {(_Float16)av.x, (_Float16)av.y, (_Float16)av.z, (_Float16)av.w};
      half4 bh = {(_Float16)bv.x, (_Float16)bv.y, (_Float16)bv.z, (_Float16)bv.w};
      half4 al = {(_Float16)(av.x - (float)ah.x), (_Float16)(av.y - (float)ah.y),
                  (_Float16)(av.z - (float)ah.z), (_Float16)(av.w - (float)ah.w)};
      half4 bl = {(_Float16)(bv.x - (float)bh.x), (_Float16)(bv.y - (float)bh.y),
                  (_Float16)(bv.z - (float)bh.z), (_Float16)(bv.w - (float)bh.w)};
      *(half4*)&Ah[row][c] = ah;
      *(half4*)&Al[row][c] = al;
      *(half4*)&Bh[row][c] = bh;
      *(half4*)&Bl[row][c] = bl;
    }
    __syncthreads();
    int ko = (lane >> 4) * 8, rr = lane & 15;
    half8 afh[4], afl[4], bfh[4], bfl[4];
#pragma unroll
    for (int i = 0; i < 4; ++i) {
      afh[i] = *(const half8*)&Ah[wm + i * 16 + rr][ko];
      afl[i] = *(const half8*)&Al[wm + i * 16 + rr][ko];
      bfh[i] = *(const half8*)&Bh[wn + i * 16 + rr][ko];
      bfl[i] = *(const half8*)&Bl[wn + i * 16 + rr][ko];
    }
#pragma unroll
    for (int i = 0; i < 4; ++i)
#pragma unroll
      for (int j = 0; j < 4; ++j) {
        acc[i][j] = __builtin_amdgcn_mfma_f32_16x16x32_f16(afl[i], bfh[j], acc[i][j], 0, 0, 0);
        acc[i][j] = __builtin_amdgcn_mfma_f32_16x16x32_f16(afh[i], bfl[j], acc[i][j], 0, 0, 0);
        acc[i][j] = __builtin_amdgcn_mfma_f32_16x16x32_f16(afh[i], bfh[j], acc[i][j], 0, 0, 0);
      }
    __syncthreads();
  }
  int cR = (lane >> 4) * 4, cC = lane & 15;
#pragma unroll
  for (int i = 0; i < 4; ++i)
#pragma unroll
    for (int j = 0; j < 4; ++j) {
      int row = mblk * 128 + wm + i * 16 + cR;
      int col = nblk * 128 + wn + j * 16 + cC;
#pragma unroll
      for (int r = 0; r < 4; ++r)
        C[(size_t)(row + r) * 2048 + col] = acc[i][j][r];
    }
}

// ---------------------------------------------------------------------------
// k_cache: f16 normalized copy (for the filter) + double 1/||k|| (for exact
// re-scoring). One wave per cache row; HBM-bound, extra math is free.
// ---------------------------------------------------------------------------
__global__ __launch_bounds__(256) void cache_norm(const float* __restrict__ kc,
                                                  _Float16* __restrict__ kn16,
                                                  double* __restrict__ kninv) {
  int w = threadIdx.x >> 6, lane = threadIdx.x & 63;
  int row = blockIdx.x * 4 + w;
  f32x2 v = *(const f32x2*)(kc + (size_t)row * DIM + lane * 2);
  double s = (double)v[0] * v[0] + (double)v[1] * v[1];
#pragma unroll
  for (int off = 32; off; off >>= 1) s += __shfl_xor(s, off);
  float inv = rsqrtf((float)s);
  half2t o = {(_Float16)(v[0] * inv), (_Float16)(v[1] * inv)};
  *(half2t*)(kn16 + (size_t)row * DIM + lane * 2) = o;
  if (lane == 0) kninv[row] = 1.0 / sqrt(s);
}

// ---------------------------------------------------------------------------
// From qkv: per-head f16 q, k_local, normalized q. Wave per (h,s).
// ---------------------------------------------------------------------------
__global__ __launch_bounds__(256) void prep_local(const float* __restrict__ qkv,
                                                  _Float16* __restrict__ q16,
                                                  _Float16* __restrict__ k16,
                                                  _Float16* __restrict__ qn16) {
  int w = threadIdx.x >> 6, lane = threadIdx.x & 63;
  int rid = blockIdx.x * 4 + w;
  int h = rid >> 9, s = rid & 511;
  const float* qp = qkv + (size_t)s * (3 * HID) + h * DIM + lane * 2;
  f32x2 q = *(const f32x2*)qp;
  f32x2 k = *(const f32x2*)(qp + HID);
  float ss = q[0] * q[0] + q[1] * q[1];
#pragma unroll
  for (int off = 32; off; off >>= 1) ss += __shfl_xor(ss, off);
  float inv = rsqrtf(ss);
  half2t qh = {(_Float16)q[0], (_Float16)q[1]};
  half2t kh = {(_Float16)k[0], (_Float16)k[1]};
  half2t qnh = {(_Float16)(q[0] * inv), (_Float16)(q[1] * inv)};
  *(half2t*)(q16 + (size_t)rid * DIM + lane * 2) = qh;
  *(half2t*)(k16 + (size_t)rid * DIM + lane * 2) = kh;
  *(half2t*)(qn16 + (size_t)rid * DIM + lane * 2) = qnh;
}

// ---------------------------------------------------------------------------
// Candidate filter: sim = Qn @ Kn^T per head via f16 MFMA; threshold 0.249
// (margin 1e-3 >> f16 error ~7e-5). Proposes candidates; never decides.
// ---------------------------------------------------------------------------
__global__ __launch_bounds__(256) void sim_cand(const _Float16* __restrict__ qn16,
                                                const _Float16* __restrict__ kn16,
                                                int* __restrict__ cnt,
                                                int* __restrict__ cidx) {
  __shared__ __align__(16) _Float16 Ks[128][136];
  __shared__ __align__(16) _Float16 Qs[64][136];
  int b = blockIdx.x;
  int h = b & 15, cblk = b >> 4;
  int t = threadIdx.x, lane = t & 63, w = t >> 6;

  const _Float16* kb = kn16 + ((size_t)(h * SCACHE + cblk * 128)) * DIM;
#pragma unroll
  for (int i = 0; i < 8; ++i) {
    int f = t + 256 * i;
    int row = f >> 4, c8 = (f & 15) * 8;
    *(uint4*)&Ks[row][c8] = *(const uint4*)(kb + (size_t)row * DIM + c8);
  }

  for (int qt = 0; qt < 8; ++qt) {
    __syncthreads();
    const _Float16* qb = qn16 + ((size_t)(h * SEQ + qt * 64)) * DIM;
#pragma unroll
    for (int i = 0; i < 4; ++i) {
      int f = t + 256 * i;
      int row = f >> 4, c8 = (f & 15) * 8;
      *(uint4*)&Qs[row][c8] = *(const uint4*)(qb + (size_t)row * DIM + c8);
    }
    __syncthreads();

    f32x4 acc[4][2] = {};
#pragma unroll
    for (int ks = 0; ks < 4; ++ks) {
      int ko = ks * 32 + (lane >> 4) * 8;
      int rr = lane & 15;
      half8 af[4], bf[2];
#pragma unroll
      for (int i = 0; i < 4; ++i) af[i] = *(const half8*)&Qs[i * 16 + rr][ko];
#pragma unroll
      for (int j = 0; j < 2; ++j) bf[j] = *(const half8*)&Ks[w * 32 + j * 16 + rr][ko];
#pragma unroll
      for (int i = 0; i < 4; ++i)
#pragma unroll
        for (int j = 0; j < 2; ++j)
          acc[i][j] = __builtin_amdgcn_mfma_f32_16x16x32_f16(af[i], bf[j], acc[i][j], 0, 0, 0);
    }
    int qrow_base = qt * 64 + ((lane >> 4) << 2);
    int key_base = cblk * 128 + w * 32 + (lane & 15);
#pragma unroll
    for (int i = 0; i < 4; ++i)
#pragma unroll
      for (int j = 0; j < 2; ++j)
#pragma unroll
        for (int r = 0; r < 4; ++r) {
          float v = acc[i][j][r];
          if (v > 0.249f) {
            int q = qrow_base + i * 16 + r;
            int rowid = h * SEQ + q;
            int pos = atomicAdd(&cnt[rowid], 1);
            if (pos < CAP) cidx[rowid * CAP + pos] = key_base + j * 16;
          }
        }
  }
}

// ---------------------------------------------------------------------------
// Candidate-parallel exact re-score + top-16 membership.
// Wave per row; lane c owns candidate c (n <= 64). Per-lane double dot
// (q loads are wave-uniform -> scalar broadcast), r = d * kninv[idx].
// Parallel rank via n shuffle-broadcast rounds; ballot-compact the selected
// set (slot order is irrelevant: softmax sums the row's own 16 slots).
// ---------------------------------------------------------------------------
__global__ __launch_bounds__(256) void select_topk(const int* __restrict__ cnt,
                                                   const int* __restrict__ cidx,
                                                   const float* __restrict__ qhi,
                                                   const float* __restrict__ kcache,
                                                   const double* __restrict__ kninv,
                                                   int* __restrict__ sel_idx,
                                                   float* __restrict__ sel_score) {
  int w = threadIdx.x >> 6, lane = threadIdx.x & 63;
  int rowid = blockIdx.x * 4 + w;
  int h = rowid >> 9, s = rowid & 511;
  const float* qp = qhi + (size_t)s * HID + h * DIM;

  // ||q|| in double (wave-cooperative, 2 elems/lane)
  f32x2 qv2 = *(const f32x2*)(qp + lane * 2);
  double qs = (double)qv2[0] * qv2[0] + (double)qv2[1] * qv2[1];
#pragma unroll
  for (int off = 32; off; off >>= 1) qs += __shfl_xor(qs, off);
  double thr = 0.25 * sqrt(qs);

  int n = min(cnt[rowid], CAP);
  int idx = 0x7fffffff;
  double r = -1e300, d = 0.0;
  if (lane < n) {
    idx = cidx[rowid * CAP + lane];
    const float* kp = kcache + ((size_t)(h * SCACHE + idx)) * DIM;
    double d0 = 0.0, d1 = 0.0;
#pragma unroll
    for (int j = 0; j < DIM; j += 8) {
      f32x4 ka = *(const f32x4*)(kp + j);
      f32x4 kb = *(const f32x4*)(kp + j + 4);
      f32x4 qa = *(const f32x4*)(qp + j);
      f32x4 qb = *(const f32x4*)(qp + j + 4);
      d0 = fma((double)qa[0], (double)ka[0], d0);
      d1 = fma((double)qa[1], (double)ka[1], d1);
      d0 = fma((double)qa[2], (double)ka[2], d0);
      d1 = fma((double)qa[3], (double)ka[3], d1);
      d0 = fma((double)qb[0], (double)kb[0], d0);
      d1 = fma((double)qb[1], (double)kb[1], d1);
      d0 = fma((double)qb[2], (double)kb[2], d0);
      d1 = fma((double)qb[3], (double)kb[3], d1);
    }
    d = d0 + d1;
    r = d * kninv[h * SCACHE + idx];
  }

  // parallel rank: rank_c = #{j : r_j > r_c  or  (r_j == r_c and idx_j < idx_c)}
  int rank = 0;
  for (int j = 0; j < n; ++j) {
    double rj = __shfl(r, j);
    int ij = __shfl(idx, j);
    if (rj > r || (rj == r && ij < idx)) ++rank;
  }
  bool sel = (lane < n) && (rank < 16) && (r > thr);
  unsigned long long m = __ballot(sel);
  int nsel = __popcll(m);
  if (sel) {
    int pos = __popcll(m & ((1ull << lane) - 1));
    sel_idx[rowid * 16 + pos] = idx;
    sel_score[rowid * 16 + pos] = (float)(d * (double)SCALE);
  }
  if (lane >= nsel && lane < 16) {
    sel_idx[rowid * 16 + lane] = 0;
    sel_score[rowid * 16 + lane] = NEG_INF;
  }
}

// ---------------------------------------------------------------------------
// Attention: one block per (h, 16-query tile). Local scores via f16 MFMA,
// fp32 softmax over 544 slots, fp32 vector PV, writes ctx[s][h*128+d].
// ---------------------------------------------------------------------------
__global__ __launch_bounds__(256) void attn(const float* __restrict__ qkv,
                                            const _Float16* __restrict__ q16,
                                            const _Float16* __restrict__ k16,
                                            const float* __restrict__ bias,
                                            const int* __restrict__ sel_idx,
                                            const float* __restrict__ sel_score,
                                            const float* __restrict__ vcache,
                                            float* __restrict__ ctx) {
  __shared__ __align__(16) float sc[16][560];
  __shared__ float invd[16];
  int b = blockIdx.x;
  int h = b & 15, qb = b >> 4;
  int q0 = qb * 16;
  int t = threadIdx.x, lane = t & 63, w = t >> 6;

  for (int i = t; i < 16 * 560; i += 256) (&sc[0][0])[i] = NEG_INF;
  __syncthreads();

  const _Float16* qbp = q16 + ((size_t)(h * SEQ + q0)) * DIM;
  half8 af[4];
#pragma unroll
  for (int ks = 0; ks < 4; ++ks)
    af[ks] = *(const half8*)(qbp + (size_t)(lane & 15) * DIM + ks * 32 + (lane >> 4) * 8);
  int nk = q0 + 16;
  for (int kt = 0; kt < nk; kt += 64) {
    int kb = kt + w * 16;
    if (kb < nk) {
      const _Float16* kp = k16 + ((size_t)(h * SEQ + kb)) * DIM;
      f32x4 acc = {};
#pragma unroll
      for (int ks = 0; ks < 4; ++ks) {
        half8 bf = *(const half8*)(kp + (size_t)(lane & 15) * DIM + ks * 32 + (lane >> 4) * 8);
        acc = __builtin_amdgcn_mfma_f32_16x16x32_f16(af[ks], bf, acc, 0, 0, 0);
      }
      int key = kb + (lane & 15);
      int r0 = (lane >> 4) * 4;
#pragma unroll
      for (int r = 0; r < 4; ++r) {
        int qrow = q0 + r0 + r;
        float sv = (key <= qrow)
                       ? acc[r] * SCALE + bias[((size_t)h * SEQ + qrow) * SEQ + key]
                       : NEG_INF;
        sc[r0 + r][key] = sv;
      }
    }
  }
  {
    int r = t >> 4, j = t & 15;
    int rowid = h * SEQ + q0 + r;
    sc[r][512 + j] = sel_score[rowid * 16 + j];
  }
  __syncthreads();

  for (int r = w * 4; r < w * 4 + 4; ++r) {
    float m = NEG_INF;
    for (int j = lane; j < 544; j += 64) m = fmaxf(m, sc[r][j]);
#pragma unroll
    for (int off = 32; off; off >>= 1) m = fmaxf(m, __shfl_xor(m, off));
    float sum = 0.f;
    for (int j = lane; j < 544; j += 64) {
      float e = __expf(sc[r][j] - m);
      sc[r][j] = e;
      sum += e;
    }
#pragma unroll
    for (int off = 32; off; off >>= 1) sum += __shfl_xor(sum, off);
    if (lane == 0) invd[r] = 1.f / sum;
  }
  __syncthreads();

  int d4 = (t & 31) * 4;
  int r0 = (t >> 5) * 2;
  f32x4 a0 = {}, a1 = {};
  const float* vb = qkv + 2 * HID + h * DIM + d4;
  for (int j4 = 0; j4 < nk; j4 += 4) {
    f32x4 w0 = *(const f32x4*)&sc[r0][j4];
    f32x4 w1 = *(const f32x4*)&sc[r0 + 1][j4];
#pragma unroll
    for (int jj = 0; jj < 4; ++jj) {
      f32x4 v = *(const f32x4*)(vb + (size_t)(j4 + jj) * (3 * HID));
      a0 += v * w0[jj];
      a1 += v * w1[jj];
    }
  }
  for (int rr = 0; rr < 2; ++rr) {
    int r = r0 + rr;
    int rowid = h * SEQ + q0 + r;
#pragma unroll
    for (int j = 0; j < 16; ++j) {
      float wv = sc[r][512 + j];
      if (wv > 0.f) {
        int idx = sel_idx[rowid * 16 + j];
        f32x4 v = *(const f32x4*)(vcache + ((size_t)(h * SCACHE + idx)) * DIM + d4);
        if (rr == 0) a0 += v * wv; else a1 += v * wv;
      }
    }
  }
  f32x4 o0 = a0 * invd[r0], o1 = a1 * invd[r0 + 1];
  *(f32x4*)(ctx + (size_t)(q0 + r0) * HID + h * DIM + d4) = o0;
  *(f32x4*)(ctx + (size_t)(q0 + r0 + 1) * HID + h * DIM + d4) = o1;
}

// ---------------------------------------------------------------------------
extern "C" void kernel_launch(void* const* d_in, const int* in_sizes, int n_in,
                              void* d_out, int out_size, void* d_ws, size_t ws_size,
                              hipStream_t stream) {
  const float* hidden = (const float*)d_in[0];
  const float* Wqkv   = (const float*)d_in[1];
  const float* Wout   = (const float*)d_in[2];
  const float* kcache = (const float*)d_in[3];
  const float* vcache = (const float*)d_in[4];
  const float* bias   = (const float*)d_in[5];

  char* ws = (char*)d_ws;
  size_t off = 0;
  float*    qkv   = (float*)(ws + off);    off += (size_t)SEQ * 3 * HID * 4;
  float*    qhi   = (float*)(ws + off);    off += (size_t)SEQ * HID * 4;
  _Float16* q16   = (_Float16*)(ws + off); off += (size_t)NHEAD * SEQ * DIM * 2;
  _Float16* k16   = (_Float16*)(ws + off); off += (size_t)NHEAD * SEQ * DIM * 2;
  _Float16* qn16  = (_Float16*)(ws + off); off += (size_t)NHEAD * SEQ * DIM * 2;
  _Float16* kn16  = (_Float16*)(ws + off); off += (size_t)NHEAD * SCACHE * DIM * 2;
  double*   kninv = (double*)(ws + off);   off += (size_t)NHEAD * SCACHE * 8;
  int*      ccnt  = (int*)(ws + off);      off += (size_t)NHEAD * SEQ * 4;
  int*      cidx  = (int*)(ws + off);      off += (size_t)NHEAD * SEQ * CAP * 4;
  int*      selidx  = (int*)(ws + off);    off += (size_t)NHEAD * SEQ * 16 * 4;
  float*    selsc   = (float*)(ws + off);  off += (size_t)NHEAD * SEQ * 16 * 4;
  float*    ctx   = (float*)(ws + off);    off += (size_t)SEQ * HID * 4;

  hipMemsetAsync(ccnt, 0, (size_t)NHEAD * SEQ * 4, stream);
  cache_norm<<<dim3(NHEAD * SCACHE / 4), dim3(256), 0, stream>>>(kcache, kn16, kninv);
  gemm_xwT<<<dim3(4 * 48), dim3(256), 0, stream>>>(hidden, Wqkv, qkv, 512, 6144, 2048, 48);
  gemm_q_hi<<<dim3(4 * 16), dim3(256), 0, stream>>>(hidden, Wqkv, qhi);
  prep_local<<<dim3(NHEAD * SEQ / 4), dim3(256), 0, stream>>>(qkv, q16, k16, qn16);
  sim_cand<<<dim3(NHEAD * 64), dim3(256), 0, stream>>>(qn16, kn16, ccnt, cidx);
  select_topk<<<dim3(NHEAD * SEQ / 4), dim3(256), 0, stream>>>(ccnt, cidx, qhi, kcache,
                                                               kninv, selidx, selsc);
  attn<<<dim3(NHEAD * 32), dim3(256), 0, stream>>>(qkv, q16, k16, bias, selidx, selsc,
                                                   vcache, ctx);
  gemm_xwT<<<dim3(4 * 16), dim3(256), 0, stream>>>(ctx, Wout, (float*)d_out, 512, 2048, 2048, 16);
}

// Round 4
// 610.482 us; speedup vs baseline: 1.2174x; 1.0135x over previous
//
#include <hip/hip_runtime.h>

typedef _Float16 half8 __attribute__((ext_vector_type(8)));
typedef _Float16 half4 __attribute__((ext_vector_type(4)));
typedef _Float16 half2t __attribute__((ext_vector_type(2)));
typedef float f32x4 __attribute__((ext_vector_type(4)));
typedef float f32x2 __attribute__((ext_vector_type(2)));

#define NHEAD 16
#define SEQ 512
#define DIM 128
#define HID 2048
#define SCACHE 8192
#define CAP 64
#define SCALE 0.08838834764831845f   // 1/sqrt(128)
#define NEG_INF (-__builtin_inff())

// ---------------------------------------------------------------------------
// Generic C[M,N] = A[M,K] @ B[N,K]^T   (fp32 in/out, f16 MFMA, fp32 accum)
// ---------------------------------------------------------------------------
__global__ __launch_bounds__(256) void gemm_xwT(const float* __restrict__ A,
                                                const float* __restrict__ B,
                                                float* __restrict__ C,
                                                int M, int N, int K, int gridN) {
  __shared__ __align__(16) _Float16 As[128][88];
  __shared__ __align__(16) _Float16 Bs[128][88];
  int b = blockIdx.x;
  int nblk = b % gridN, mblk = b / gridN;
  int t = threadIdx.x;
  int lane = t & 63, wid = t >> 6;
  int wm = (wid >> 1) * 64, wn = (wid & 1) * 64;
  f32x4 acc[4][4] = {};
  const float* Ab = A + (size_t)mblk * 128 * K;
  const float* Bb = B + (size_t)nblk * 128 * K;
  int rowS = t >> 4, c4 = (t & 15) * 4;

  for (int k0 = 0; k0 < K; k0 += 64) {
#pragma unroll
    for (int i = 0; i < 8; ++i) {
      int row = rowS + 16 * i;
      float4 av = *(const float4*)(Ab + (size_t)row * K + k0 + c4);
      float4 bv = *(const float4*)(Bb + (size_t)row * K + k0 + c4);
      half4 ah = {(_Float16)av.x, (_Float16)av.y, (_Float16)av.z, (_Float16)av.w};
      half4 bh = {(_Float16)bv.x, (_Float16)bv.y, (_Float16)bv.z, (_Float16)bv.w};
      *(half4*)&As[row][c4] = ah;
      *(half4*)&Bs[row][c4] = bh;
    }
    __syncthreads();
#pragma unroll
    for (int ks = 0; ks < 2; ++ks) {
      int ko = ks * 32 + (lane >> 4) * 8;
      int rr = lane & 15;
      half8 af[4], bf[4];
#pragma unroll
      for (int i = 0; i < 4; ++i) af[i] = *(const half8*)&As[wm + i * 16 + rr][ko];
#pragma unroll
      for (int j = 0; j < 4; ++j) bf[j] = *(const half8*)&Bs[wn + j * 16 + rr][ko];
#pragma unroll
      for (int i = 0; i < 4; ++i)
#pragma unroll
        for (int j = 0; j < 4; ++j)
          acc[i][j] = __builtin_amdgcn_mfma_f32_16x16x32_f16(af[i], bf[j], acc[i][j], 0, 0, 0);
    }
    __syncthreads();
  }
  int cR = (lane >> 4) * 4, cC = lane & 15;
#pragma unroll
  for (int i = 0; i < 4; ++i)
#pragma unroll
    for (int j = 0; j < 4; ++j) {
      int row = mblk * 128 + wm + i * 16 + cR;
      int col = nblk * 128 + wn + j * 16 + cC;
#pragma unroll
      for (int r = 0; r < 4; ++r)
        C[(size_t)(row + r) * N + col] = acc[i][j][r];
    }
}

// ---------------------------------------------------------------------------
// q-third of QKV at fp32 accuracy via 3-term f16 split MFMA.
// ---------------------------------------------------------------------------
__global__ __launch_bounds__(256) void gemm_q_hi(const float* __restrict__ A,
                                                 const float* __restrict__ B,
                                                 float* __restrict__ C) {
  __shared__ __align__(16) _Float16 Ah[128][40], Al[128][40];
  __shared__ __align__(16) _Float16 Bh[128][40], Bl[128][40];
  int b = blockIdx.x;
  int nblk = b & 15, mblk = b >> 4;
  int t = threadIdx.x, lane = t & 63, wid = t >> 6;
  int wm = (wid >> 1) * 64, wn = (wid & 1) * 64;
  f32x4 acc[4][4] = {};
  const float* Ab = A + (size_t)mblk * 128 * 2048;
  const float* Bb = B + (size_t)nblk * 128 * 2048;

  for (int k0 = 0; k0 < 2048; k0 += 32) {
#pragma unroll
    for (int i = 0; i < 4; ++i) {
      int f = t + 256 * i;
      int row = f >> 3, c = (f & 7) * 4;
      float4 av = *(const float4*)(Ab + (size_t)row * 2048 + k0 + c);
      float4 bv = *(const float4*)(Bb + (size_t)row * 2048 + k0 + c);
      half4 ah = {(_Float16)av.x, (_Float16)av.y, (_Float16)av.z, (_Float16)av.w};
      half4 bh = {(_Float16)bv.x, (_Float16)bv.y, (_Float16)bv.z, (_Float16)bv.w};
      half4 al = {(_Float16)(av.x - (float)ah.x), (_Float16)(av.y - (float)ah.y),
                  (_Float16)(av.z - (float)ah.z), (_Float16)(av.w - (float)ah.w)};
      half4 bl = {(_Float16)(bv.x - (float)bh.x), (_Float16)(bv.y - (float)bh.y),
                  (_Float16)(bv.z - (float)bh.z), (_Float16)(bv.w - (float)bh.w)};
      *(half4*)&Ah[row][c] = ah;
      *(half4*)&Al[row][c] = al;
      *(half4*)&Bh[row][c] = bh;
      *(half4*)&Bl[row][c] = bl;
    }
    __syncthreads();
    int ko = (lane >> 4) * 8, rr = lane & 15;
    half8 afh[4], afl[4], bfh[4], bfl[4];
#pragma unroll
    for (int i = 0; i < 4; ++i) {
      afh[i] = *(const half8*)&Ah[wm + i * 16 + rr][ko];
      afl[i] = *(const half8*)&Al[wm + i * 16 + rr][ko];
      bfh[i] = *(const half8*)&Bh[wn + i * 16 + rr][ko];
      bfl[i] = *(const half8*)&Bl[wn + i * 16 + rr][ko];
    }
#pragma unroll
    for (int i = 0; i < 4; ++i)
#pragma unroll
      for (int j = 0; j < 4; ++j) {
        acc[i][j] = __builtin_amdgcn_mfma_f32_16x16x32_f16(afl[i], bfh[j], acc[i][j], 0, 0, 0);
        acc[i][j] = __builtin_amdgcn_mfma_f32_16x16x32_f16(afh[i], bfl[j], acc[i][j], 0, 0, 0);
        acc[i][j] = __builtin_amdgcn_mfma_f32_16x16x32_f16(afh[i], bfh[j], acc[i][j], 0, 0, 0);
      }
    __syncthreads();
  }
  int cR = (lane >> 4) * 4, cC = lane & 15;
#pragma unroll
  for (int i = 0; i < 4; ++i)
#pragma unroll
    for (int j = 0; j < 4; ++j) {
      int row = mblk * 128 + wm + i * 16 + cR;
      int col = nblk * 128 + wn + j * 16 + cC;
#pragma unroll
      for (int r = 0; r < 4; ++r)
        C[(size_t)(row + r) * 2048 + col] = acc[i][j][r];
    }
}

// ---------------------------------------------------------------------------
// k_cache: f16 normalized copy (filter) + double 1/||k|| (exact re-scoring).
// ---------------------------------------------------------------------------
__global__ __launch_bounds__(256) void cache_norm(const float* __restrict__ kc,
                                                  _Float16* __restrict__ kn16,
                                                  double* __restrict__ kninv) {
  int w = threadIdx.x >> 6, lane = threadIdx.x & 63;
  int row = blockIdx.x * 4 + w;
  f32x2 v = *(const f32x2*)(kc + (size_t)row * DIM + lane * 2);
  double s = (double)v[0] * v[0] + (double)v[1] * v[1];
#pragma unroll
  for (int off = 32; off; off >>= 1) s += __shfl_xor(s, off);
  float inv = rsqrtf((float)s);
  half2t o = {(_Float16)(v[0] * inv), (_Float16)(v[1] * inv)};
  *(half2t*)(kn16 + (size_t)row * DIM + lane * 2) = o;
  if (lane == 0) kninv[row] = 1.0 / sqrt(s);
}

// ---------------------------------------------------------------------------
// From qkv: per-head f16 q, k_local, normalized q. Wave per (h,s).
// ---------------------------------------------------------------------------
__global__ __launch_bounds__(256) void prep_local(const float* __restrict__ qkv,
                                                  _Float16* __restrict__ q16,
                                                  _Float16* __restrict__ k16,
                                                  _Float16* __restrict__ qn16) {
  int w = threadIdx.x >> 6, lane = threadIdx.x & 63;
  int rid = blockIdx.x * 4 + w;
  int h = rid >> 9, s = rid & 511;
  const float* qp = qkv + (size_t)s * (3 * HID) + h * DIM + lane * 2;
  f32x2 q = *(const f32x2*)qp;
  f32x2 k = *(const f32x2*)(qp + HID);
  float ss = q[0] * q[0] + q[1] * q[1];
#pragma unroll
  for (int off = 32; off; off >>= 1) ss += __shfl_xor(ss, off);
  float inv = rsqrtf(ss);
  half2t qh = {(_Float16)q[0], (_Float16)q[1]};
  half2t kh = {(_Float16)k[0], (_Float16)k[1]};
  half2t qnh = {(_Float16)(q[0] * inv), (_Float16)(q[1] * inv)};
  *(half2t*)(q16 + (size_t)rid * DIM + lane * 2) = qh;
  *(half2t*)(k16 + (size_t)rid * DIM + lane * 2) = kh;
  *(half2t*)(qn16 + (size_t)rid * DIM + lane * 2) = qnh;
}

// ---------------------------------------------------------------------------
// Candidate filter: sim = Qn @ Kn^T per head via f16 MFMA; threshold 0.249.
// ---------------------------------------------------------------------------
__global__ __launch_bounds__(256) void sim_cand(const _Float16* __restrict__ qn16,
                                                const _Float16* __restrict__ kn16,
                                                int* __restrict__ cnt,
                                                int* __restrict__ cidx) {
  __shared__ __align__(16) _Float16 Ks[128][136];
  __shared__ __align__(16) _Float16 Qs[64][136];
  int b = blockIdx.x;
  int h = b & 15, cblk = b >> 4;
  int t = threadIdx.x, lane = t & 63, w = t >> 6;

  const _Float16* kb = kn16 + ((size_t)(h * SCACHE + cblk * 128)) * DIM;
#pragma unroll
  for (int i = 0; i < 8; ++i) {
    int f = t + 256 * i;
    int row = f >> 4, c8 = (f & 15) * 8;
    *(uint4*)&Ks[row][c8] = *(const uint4*)(kb + (size_t)row * DIM + c8);
  }

  for (int qt = 0; qt < 8; ++qt) {
    __syncthreads();
    const _Float16* qb = qn16 + ((size_t)(h * SEQ + qt * 64)) * DIM;
#pragma unroll
    for (int i = 0; i < 4; ++i) {
      int f = t + 256 * i;
      int row = f >> 4, c8 = (f & 15) * 8;
      *(uint4*)&Qs[row][c8] = *(const uint4*)(qb + (size_t)row * DIM + c8);
    }
    __syncthreads();

    f32x4 acc[4][2] = {};
#pragma unroll
    for (int ks = 0; ks < 4; ++ks) {
      int ko = ks * 32 + (lane >> 4) * 8;
      int rr = lane & 15;
      half8 af[4], bf[2];
#pragma unroll
      for (int i = 0; i < 4; ++i) af[i] = *(const half8*)&Qs[i * 16 + rr][ko];
#pragma unroll
      for (int j = 0; j < 2; ++j) bf[j] = *(const half8*)&Ks[w * 32 + j * 16 + rr][ko];
#pragma unroll
      for (int i = 0; i < 4; ++i)
#pragma unroll
        for (int j = 0; j < 2; ++j)
          acc[i][j] = __builtin_amdgcn_mfma_f32_16x16x32_f16(af[i], bf[j], acc[i][j], 0, 0, 0);
    }
    int qrow_base = qt * 64 + ((lane >> 4) << 2);
    int key_base = cblk * 128 + w * 32 + (lane & 15);
#pragma unroll
    for (int i = 0; i < 4; ++i)
#pragma unroll
      for (int j = 0; j < 2; ++j)
#pragma unroll
        for (int r = 0; r < 4; ++r) {
          float v = acc[i][j][r];
          if (v > 0.249f) {
            int q = qrow_base + i * 16 + r;
            int rowid = h * SEQ + q;
            int pos = atomicAdd(&cnt[rowid], 1);
            if (pos < CAP) cidx[rowid * CAP + pos] = key_base + j * 16;
          }
        }
  }
}

// ---------------------------------------------------------------------------
// Candidate-parallel exact re-score + top-16 membership (double precision).
// ---------------------------------------------------------------------------
__global__ __launch_bounds__(256) void select_topk(const int* __restrict__ cnt,
                                                   const int* __restrict__ cidx,
                                                   const float* __restrict__ qhi,
                                                   const float* __restrict__ kcache,
                                                   const double* __restrict__ kninv,
                                                   int* __restrict__ sel_idx,
                                                   float* __restrict__ sel_score) {
  int w = threadIdx.x >> 6, lane = threadIdx.x & 63;
  int rowid = blockIdx.x * 4 + w;
  int h = rowid >> 9, s = rowid & 511;
  const float* qp = qhi + (size_t)s * HID + h * DIM;

  f32x2 qv2 = *(const f32x2*)(qp + lane * 2);
  double qs = (double)qv2[0] * qv2[0] + (double)qv2[1] * qv2[1];
#pragma unroll
  for (int off = 32; off; off >>= 1) qs += __shfl_xor(qs, off);
  double thr = 0.25 * sqrt(qs);

  int n = min(cnt[rowid], CAP);
  int idx = 0x7fffffff;
  double r = -1e300, d = 0.0;
  if (lane < n) {
    idx = cidx[rowid * CAP + lane];
    const float* kp = kcache + ((size_t)(h * SCACHE + idx)) * DIM;
    double d0 = 0.0, d1 = 0.0;
#pragma unroll
    for (int j = 0; j < DIM; j += 8) {
      f32x4 ka = *(const f32x4*)(kp + j);
      f32x4 kb = *(const f32x4*)(kp + j + 4);
      f32x4 qa = *(const f32x4*)(qp + j);
      f32x4 qb = *(const f32x4*)(qp + j + 4);
      d0 = fma((double)qa[0], (double)ka[0], d0);
      d1 = fma((double)qa[1], (double)ka[1], d1);
      d0 = fma((double)qa[2], (double)ka[2], d0);
      d1 = fma((double)qa[3], (double)ka[3], d1);
      d0 = fma((double)qb[0], (double)kb[0], d0);
      d1 = fma((double)qb[1], (double)kb[1], d1);
      d0 = fma((double)qb[2], (double)kb[2], d0);
      d1 = fma((double)qb[3], (double)kb[3], d1);
    }
    d = d0 + d1;
    r = d * kninv[h * SCACHE + idx];
  }

  int rank = 0;
  for (int j = 0; j < n; ++j) {
    double rj = __shfl(r, j);
    int ij = __shfl(idx, j);
    if (rj > r || (rj == r && ij < idx)) ++rank;
  }
  bool sel = (lane < n) && (rank < 16) && (r > thr);
  unsigned long long m = __ballot(sel);
  int nsel = __popcll(m);
  if (sel) {
    int pos = __popcll(m & ((1ull << lane) - 1));
    sel_idx[rowid * 16 + pos] = idx;
    sel_score[rowid * 16 + pos] = (float)(d * (double)SCALE);
  }
  if (lane >= nsel && lane < 16) {
    sel_idx[rowid * 16 + lane] = 0;
    sel_score[rowid * 16 + lane] = NEG_INF;
  }
}

// ---------------------------------------------------------------------------
// Flash-style local attention, stage 1: one block per (h, 16-q tile, 128-key
// chunk). Scores via f16 MFMA (K frags from global), chunk softmax (m,l),
// P f16 -> LDS, PV via MFMA vs LDS-staged V^T. 1280 balanced blocks.
// Tile enumeration per head: qb<8:1 chunk, <16:2, <24:3, <32:4 (80 tiles).
// ---------------------------------------------------------------------------
__global__ __launch_bounds__(256) void attn_part(const float* __restrict__ qkv,
                                                 const _Float16* __restrict__ q16,
                                                 const _Float16* __restrict__ k16,
                                                 const float* __restrict__ bias,
                                                 float* __restrict__ part_m,
                                                 float* __restrict__ part_l,
                                                 float* __restrict__ part_o) {
  __shared__ __align__(16) _Float16 Vs[128][136];  // V^T: [dim][key]
  __shared__ __align__(16) _Float16 Ps[16][136];   // P:   [q][key]
  __shared__ float mred[16][4], lred[16][4];

  int pb = blockIdx.x;
  int tt = pb % 80, h = pb / 80;
  int qb, cb;
  if (tt < 8)       { qb = tt;                cb = 0; }
  else if (tt < 24) { int u = tt - 8;  qb = 8 + (u >> 1); cb = u & 1; }
  else if (tt < 48) { int u = tt - 24; int q3 = u / 3; qb = 16 + q3; cb = u - q3 * 3; }
  else              { int u = tt - 48; qb = 24 + (u >> 2); cb = u & 3; }
  int q0 = qb * 16, kc0 = cb * 128;

  int t = threadIdx.x, lane = t & 63, w = t >> 6;
  int quad = lane >> 4, col = lane & 15;

  // stage V^T (keys kc0..kc0+127 always within SEQ)
  const float* vbase = qkv + 2 * HID + h * DIM;
#pragma unroll
  for (int i = 0; i < 16; ++i) {
    int idx = t + 256 * i;
    int key = idx & 127, dg = idx >> 7;
    f32x4 vv = *(const f32x4*)(vbase + (size_t)(kc0 + key) * (3 * HID) + dg * 4);
#pragma unroll
    for (int e = 0; e < 4; ++e) Vs[dg * 4 + e][key] = (_Float16)vv[e];
  }

  // Q frags (A: m=col, k=ks*32+quad*8..+7)
  const _Float16* qbp = q16 + ((size_t)(h * SEQ + q0)) * DIM;
  half8 af[4];
#pragma unroll
  for (int ks = 0; ks < 4; ++ks)
    af[ks] = *(const half8*)(qbp + (size_t)col * DIM + ks * 32 + quad * 8);

  // scores: wave w -> local keys [w*32, w*32+32)
  f32x4 acc[2] = {};
#pragma unroll
  for (int jn = 0; jn < 2; ++jn) {
    const _Float16* kp = k16 + ((size_t)(h * SEQ + kc0 + w * 32 + jn * 16 + col)) * DIM;
#pragma unroll
    for (int ks = 0; ks < 4; ++ks) {
      half8 bf = *(const half8*)(kp + ks * 32 + quad * 8);
      acc[jn] = __builtin_amdgcn_mfma_f32_16x16x32_f16(af[ks], bf, acc[jn], 0, 0, 0);
    }
  }
  float s[2][4];
#pragma unroll
  for (int jn = 0; jn < 2; ++jn) {
    int keyg = kc0 + w * 32 + jn * 16 + col;
#pragma unroll
    for (int r = 0; r < 4; ++r) {
      int qrow = q0 + quad * 4 + r;
      float sv = NEG_INF;
      if (keyg <= qrow)
        sv = acc[jn][r] * SCALE + bias[((size_t)h * SEQ + qrow) * SEQ + keyg];
      s[jn][r] = sv;
    }
  }

  // per-wave row max -> block row max
  float mw[4];
#pragma unroll
  for (int r = 0; r < 4; ++r) {
    float m = fmaxf(s[0][r], s[1][r]);
#pragma unroll
    for (int off = 1; off < 16; off <<= 1) m = fmaxf(m, __shfl_xor(m, off));
    mw[r] = m;
  }
  if (col == 0)
#pragma unroll
    for (int r = 0; r < 4; ++r) mred[quad * 4 + r][w] = mw[r];
  __syncthreads();

  float M[4];
#pragma unroll
  for (int r = 0; r < 4; ++r) {
    int row = quad * 4 + r;
    float m = fmaxf(fmaxf(mred[row][0], mred[row][1]),
                    fmaxf(mred[row][2], mred[row][3]));
    M[r] = m;
    float p0 = __expf(s[0][r] - m);
    float p1 = __expf(s[1][r] - m);
    Ps[row][w * 32 + col] = (_Float16)p0;
    Ps[row][w * 32 + 16 + col] = (_Float16)p1;
    float l = p0 + p1;
#pragma unroll
    for (int off = 1; off < 16; off <<= 1) l += __shfl_xor(l, off);
    if (col == 0) lred[row][w] = l;
  }
  if (w == 0 && col == 0)
#pragma unroll
    for (int r = 0; r < 4; ++r) part_m[pb * 16 + quad * 4 + r] = M[r];
  __syncthreads();

  // PV: wave w -> dims [w*32, w*32+32); contraction over 128 key slots
  f32x4 o[2] = {};
#pragma unroll
  for (int jn = 0; jn < 2; ++jn) {
#pragma unroll
    for (int ks = 0; ks < 4; ++ks) {
      half8 a = *(const half8*)&Ps[col][ks * 32 + quad * 8];
      half8 bv = *(const half8*)&Vs[w * 32 + jn * 16 + col][ks * 32 + quad * 8];
      o[jn] = __builtin_amdgcn_mfma_f32_16x16x32_f16(a, bv, o[jn], 0, 0, 0);
    }
  }
#pragma unroll
  for (int jn = 0; jn < 2; ++jn)
#pragma unroll
    for (int r = 0; r < 4; ++r)
      part_o[((size_t)pb * 16 + quad * 4 + r) * 128 + w * 32 + jn * 16 + col] = o[jn][r];
  if (t < 16)
    part_l[pb * 16 + t] = lred[t][0] + lred[t][1] + lred[t][2] + lred[t][3];
}

// ---------------------------------------------------------------------------
// Flash merge: wave per (h,q) row. Merge <=4 local partials + 16 cache slots
// (coalesced 512B vcache gathers). Deterministic, fp32.
// ---------------------------------------------------------------------------
__global__ __launch_bounds__(256) void attn_merge(const float* __restrict__ part_m,
                                                  const float* __restrict__ part_l,
                                                  const float* __restrict__ part_o,
                                                  const int* __restrict__ sel_idx,
                                                  const float* __restrict__ sel_score,
                                                  const float* __restrict__ vcache,
                                                  float* __restrict__ ctx) {
  int w = threadIdx.x >> 6, lane = threadIdx.x & 63;
  int row = blockIdx.x * 4 + w;  // h*512+q
  int h = row >> 9, q = row & 511;
  int qb = q >> 4, r = q & 15;
  int base = (qb < 8) ? qb
           : (qb < 16) ? 8 + 2 * (qb - 8)
           : (qb < 24) ? 24 + 3 * (qb - 16)
                       : 48 + 4 * (qb - 24);
  int ncb = (qb >> 3) + 1;
  int pb0 = h * 80 + base;

  float scv[16], mc = NEG_INF;
#pragma unroll
  for (int j = 0; j < 16; ++j) {
    scv[j] = sel_score[row * 16 + j];
    mc = fmaxf(mc, scv[j]);
  }
  float mi[4];
  float M = mc;
  for (int i = 0; i < ncb; ++i) {
    mi[i] = part_m[(pb0 + i) * 16 + r];
    M = fmaxf(M, mi[i]);
  }
  f32x2 O = {0.f, 0.f};
  float L = 0.f;
  for (int i = 0; i < ncb; ++i) {
    float sc = __expf(mi[i] - M);
    f32x2 ov = *(const f32x2*)(part_o + ((size_t)(pb0 + i) * 16 + r) * 128 + lane * 2);
    O += ov * sc;
    L += part_l[(pb0 + i) * 16 + r] * sc;
  }
#pragma unroll
  for (int j = 0; j < 16; ++j) {
    if (scv[j] > NEG_INF) {
      float wv = __expf(scv[j] - M);
      int idx = sel_idx[row * 16 + j];
      f32x2 v = *(const f32x2*)(vcache + ((size_t)(h * SCACHE + idx)) * DIM + lane * 2);
      O += v * wv;
      L += wv;
    }
  }
  f32x2 res = O * (1.f / L);
  *(f32x2*)(ctx + (size_t)q * HID + h * DIM + lane * 2) = res;
}

// ---------------------------------------------------------------------------
extern "C" void kernel_launch(void* const* d_in, const int* in_sizes, int n_in,
                              void* d_out, int out_size, void* d_ws, size_t ws_size,
                              hipStream_t stream) {
  const float* hidden = (const float*)d_in[0];
  const float* Wqkv   = (const float*)d_in[1];
  const float* Wout   = (const float*)d_in[2];
  const float* kcache = (const float*)d_in[3];
  const float* vcache = (const float*)d_in[4];
  const float* bias   = (const float*)d_in[5];

  char* ws = (char*)d_ws;
  size_t off = 0;
  float*    qkv   = (float*)(ws + off);    off += (size_t)SEQ * 3 * HID * 4;
  float*    qhi   = (float*)(ws + off);    off += (size_t)SEQ * HID * 4;
  _Float16* q16   = (_Float16*)(ws + off); off += (size_t)NHEAD * SEQ * DIM * 2;
  _Float16* k16   = (_Float16*)(ws + off); off += (size_t)NHEAD * SEQ * DIM * 2;
  _Float16* qn16  = (_Float16*)(ws + off); off += (size_t)NHEAD * SEQ * DIM * 2;
  _Float16* kn16  = (_Float16*)(ws + off); off += (size_t)NHEAD * SCACHE * DIM * 2;
  double*   kninv = (double*)(ws + off);   off += (size_t)NHEAD * SCACHE * 8;
  int*      ccnt  = (int*)(ws + off);      off += (size_t)NHEAD * SEQ * 4;
  int*      cidx  = (int*)(ws + off);      off += (size_t)NHEAD * SEQ * CAP * 4;
  int*      selidx  = (int*)(ws + off);    off += (size_t)NHEAD * SEQ * 16 * 4;
  float*    selsc   = (float*)(ws + off);  off += (size_t)NHEAD * SEQ * 16 * 4;
  float*    ctx   = (float*)(ws + off);    off += (size_t)SEQ * HID * 4;
  float*    pm    = (float*)(ws + off);    off += (size_t)1280 * 16 * 4;
  float*    pl    = (float*)(ws + off);    off += (size_t)1280 * 16 * 4;
  float*    po    = (float*)(ws + off);    off += (size_t)1280 * 16 * 128 * 4;

  hipMemsetAsync(ccnt, 0, (size_t)NHEAD * SEQ * 4, stream);
  cache_norm<<<dim3(NHEAD * SCACHE / 4), dim3(256), 0, stream>>>(kcache, kn16, kninv);
  gemm_xwT<<<dim3(4 * 48), dim3(256), 0, stream>>>(hidden, Wqkv, qkv, 512, 6144, 2048, 48);
  gemm_q_hi<<<dim3(4 * 16), dim3(256), 0, stream>>>(hidden, Wqkv, qhi);
  prep_local<<<dim3(NHEAD * SEQ / 4), dim3(256), 0, stream>>>(qkv, q16, k16, qn16);
  sim_cand<<<dim3(NHEAD * 64), dim3(256), 0, stream>>>(qn16, kn16, ccnt, cidx);
  select_topk<<<dim3(NHEAD * SEQ / 4), dim3(256), 0, stream>>>(ccnt, cidx, qhi, kcache,
                                                               kninv, selidx, selsc);
  attn_part<<<dim3(16 * 80), dim3(256), 0, stream>>>(qkv, q16, k16, bias, pm, pl, po);
  attn_merge<<<dim3(NHEAD * SEQ / 4), dim3(256), 0, stream>>>(pm, pl, po, selidx, selsc,
                                                              vcache, ctx);
  gemm_xwT<<<dim3(4 * 16), dim3(256), 0, stream>>>(ctx, Wout, (float*)d_out, 512, 2048, 2048, 16);
}

// Round 6
// 577.046 us; speedup vs baseline: 1.2879x; 1.0579x over previous
//
#include <hip/hip_runtime.h>

typedef _Float16 half8 __attribute__((ext_vector_type(8)));
typedef _Float16 half4 __attribute__((ext_vector_type(4)));
typedef _Float16 half2t __attribute__((ext_vector_type(2)));
typedef float f32x4 __attribute__((ext_vector_type(4)));
typedef float f32x2 __attribute__((ext_vector_type(2)));

#define NHEAD 16
#define SEQ 512
#define DIM 128
#define HID 2048
#define SCACHE 8192
#define CAP 64
#define SCALE 0.08838834764831845f   // 1/sqrt(128)
#define NEG_INF (-__builtin_inff())

// ---------------------------------------------------------------------------
// Generic C[M,N'] tile GEMM: C = A[M,K] @ B[N,K]^T (fp32 in/out, f16 MFMA).
// Nst = row stride of C (lets k/v write into qkv at stride 6144).
// ---------------------------------------------------------------------------
__global__ __launch_bounds__(256) void gemm_xwT(const float* __restrict__ A,
                                                const float* __restrict__ B,
                                                float* __restrict__ C,
                                                int Nst, int K, int gridN) {
  __shared__ __align__(16) _Float16 As[128][84];
  __shared__ __align__(16) _Float16 Bs[128][84];
  int b = blockIdx.x;
  int nblk = b % gridN, mblk = b / gridN;
  int t = threadIdx.x;
  int lane = t & 63, wid = t >> 6;
  int wm = (wid >> 1) * 64, wn = (wid & 1) * 64;
  f32x4 acc[4][4] = {};
  const float* Ab = A + (size_t)mblk * 128 * K;
  const float* Bb = B + (size_t)nblk * 128 * K;
  int rowS = t >> 4, c4 = (t & 15) * 4;

  for (int k0 = 0; k0 < K; k0 += 64) {
#pragma unroll
    for (int i = 0; i < 8; ++i) {
      int row = rowS + 16 * i;
      float4 av = *(const float4*)(Ab + (size_t)row * K + k0 + c4);
      float4 bv = *(const float4*)(Bb + (size_t)row * K + k0 + c4);
      half4 ah = {(_Float16)av.x, (_Float16)av.y, (_Float16)av.z, (_Float16)av.w};
      half4 bh = {(_Float16)bv.x, (_Float16)bv.y, (_Float16)bv.z, (_Float16)bv.w};
      *(half4*)&As[row][c4] = ah;
      *(half4*)&Bs[row][c4] = bh;
    }
    __syncthreads();
#pragma unroll
    for (int ks = 0; ks < 2; ++ks) {
      int ko = ks * 32 + (lane >> 4) * 8;
      int rr = lane & 15;
      half8 af[4], bf[4];
#pragma unroll
      for (int i = 0; i < 4; ++i) af[i] = *(const half8*)&As[wm + i * 16 + rr][ko];
#pragma unroll
      for (int j = 0; j < 4; ++j) bf[j] = *(const half8*)&Bs[wn + j * 16 + rr][ko];
#pragma unroll
      for (int i = 0; i < 4; ++i)
#pragma unroll
        for (int j = 0; j < 4; ++j)
          acc[i][j] = __builtin_amdgcn_mfma_f32_16x16x32_f16(af[i], bf[j], acc[i][j], 0, 0, 0);
    }
    __syncthreads();
  }
  int cR = (lane >> 4) * 4, cC = lane & 15;
#pragma unroll
  for (int i = 0; i < 4; ++i)
#pragma unroll
    for (int j = 0; j < 4; ++j) {
      int row = mblk * 128 + wm + i * 16 + cR;
      int col = nblk * 128 + wn + j * 16 + cC;
#pragma unroll
      for (int r = 0; r < 4; ++r)
        C[(size_t)(row + r) * Nst + col] = acc[i][j][r];
    }
}

// ---------------------------------------------------------------------------
// q-third at fp32 accuracy via 3-term f16 split MFMA.
// BIT-IDENTICAL accumulation to the round-2/3/4 version (same per-element
// conversions, same K order 0..2048 step 32, same 3-MFMA chain, acc=0 init) —
// selection decisions depend on these exact bits. Retiled 128x128 -> 64x64
// (grid 64 -> 256 blocks) for occupancy; tiling does not touch the chain.
// Writes q directly into qkv cols 0..2047 (stride 6144).
// ---------------------------------------------------------------------------
__global__ __launch_bounds__(256) void gemm_q_hi(const float* __restrict__ A,
                                                 const float* __restrict__ B,
                                                 float* __restrict__ C) {
  __shared__ __align__(16) _Float16 Ah[64][40], Al[64][40];
  __shared__ __align__(16) _Float16 Bh[64][40], Bl[64][40];
  int b = blockIdx.x;
  int nblk = b & 31, mblk = b >> 5;   // N: 32x64, M: 8x64
  int t = threadIdx.x, lane = t & 63, wid = t >> 6;
  int wm = (wid >> 1) * 32, wn = (wid & 1) * 32;
  int quad = lane >> 4, rr = lane & 15;
  f32x4 acc[2][2] = {};
  const float* Ab = A + (size_t)mblk * 64 * 2048;
  const float* Bb = B + (size_t)nblk * 64 * 2048;
  int rowS = t >> 2, cS = (t & 3) * 8;

  for (int k0 = 0; k0 < 2048; k0 += 32) {
#pragma unroll
    for (int half = 0; half < 2; ++half) {
      int c = cS + half * 4;
      float4 av = *(const float4*)(Ab + (size_t)rowS * 2048 + k0 + c);
      float4 bv = *(const float4*)(Bb + (size_t)rowS * 2048 + k0 + c);
      half4 ah = {(_Float16)av.x, (_Float16)av.y, (_Float16)av.z, (_Float16)av.w};
      half4 bh = {(_Float16)bv.x, (_Float16)bv.y, (_Float16)bv.z, (_Float16)bv.w};
      half4 al = {(_Float16)(av.x - (float)ah.x), (_Float16)(av.y - (float)ah.y),
                  (_Float16)(av.z - (float)ah.z), (_Float16)(av.w - (float)ah.w)};
      half4 bl = {(_Float16)(bv.x - (float)bh.x), (_Float16)(bv.y - (float)bh.y),
                  (_Float16)(bv.z - (float)bh.z), (_Float16)(bv.w - (float)bh.w)};
      *(half4*)&Ah[rowS][c] = ah;
      *(half4*)&Al[rowS][c] = al;
      *(half4*)&Bh[rowS][c] = bh;
      *(half4*)&Bl[rowS][c] = bl;
    }
    __syncthreads();
    int ko = quad * 8;
    half8 afh[2], afl[2], bfh[2], bfl[2];
#pragma unroll
    for (int i = 0; i < 2; ++i) {
      afh[i] = *(const half8*)&Ah[wm + i * 16 + rr][ko];
      afl[i] = *(const half8*)&Al[wm + i * 16 + rr][ko];
      bfh[i] = *(const half8*)&Bh[wn + i * 16 + rr][ko];
      bfl[i] = *(const half8*)&Bl[wn + i * 16 + rr][ko];
    }
#pragma unroll
    for (int i = 0; i < 2; ++i)
#pragma unroll
      for (int j = 0; j < 2; ++j) {
        acc[i][j] = __builtin_amdgcn_mfma_f32_16x16x32_f16(afl[i], bfh[j], acc[i][j], 0, 0, 0);
        acc[i][j] = __builtin_amdgcn_mfma_f32_16x16x32_f16(afh[i], bfl[j], acc[i][j], 0, 0, 0);
        acc[i][j] = __builtin_amdgcn_mfma_f32_16x16x32_f16(afh[i], bfh[j], acc[i][j], 0, 0, 0);
      }
    __syncthreads();
  }
  int cR = quad * 4;
#pragma unroll
  for (int i = 0; i < 2; ++i)
#pragma unroll
    for (int j = 0; j < 2; ++j) {
      int row = mblk * 64 + wm + i * 16 + cR;
      int col = nblk * 64 + wn + j * 16 + rr;
#pragma unroll
      for (int r = 0; r < 4; ++r)
        C[(size_t)(row + r) * (3 * HID) + col] = acc[i][j][r];
    }
}

// ---------------------------------------------------------------------------
// k_cache: f16 normalized copy (filter) + double 1/||k|| (exact re-scoring).
// ---------------------------------------------------------------------------
__global__ __launch_bounds__(256) void cache_norm(const float* __restrict__ kc,
                                                  _Float16* __restrict__ kn16,
                                                  double* __restrict__ kninv) {
  int w = threadIdx.x >> 6, lane = threadIdx.x & 63;
  int row = blockIdx.x * 4 + w;
  f32x2 v = *(const f32x2*)(kc + (size_t)row * DIM + lane * 2);
  double s = (double)v[0] * v[0] + (double)v[1] * v[1];
#pragma unroll
  for (int off = 32; off; off >>= 1) s += __shfl_xor(s, off);
  float inv = rsqrtf((float)s);
  half2t o = {(_Float16)(v[0] * inv), (_Float16)(v[1] * inv)};
  *(half2t*)(kn16 + (size_t)row * DIM + lane * 2) = o;
  if (lane == 0) kninv[row] = 1.0 / sqrt(s);
}

// ---------------------------------------------------------------------------
// From qkv: per-head f16 q, k_local, normalized q. Wave per (h,s).
// ---------------------------------------------------------------------------
__global__ __launch_bounds__(256) void prep_local(const float* __restrict__ qkv,
                                                  _Float16* __restrict__ q16,
                                                  _Float16* __restrict__ k16,
                                                  _Float16* __restrict__ qn16) {
  int w = threadIdx.x >> 6, lane = threadIdx.x & 63;
  int rid = blockIdx.x * 4 + w;
  int h = rid >> 9, s = rid & 511;
  const float* qp = qkv + (size_t)s * (3 * HID) + h * DIM + lane * 2;
  f32x2 q = *(const f32x2*)qp;
  f32x2 k = *(const f32x2*)(qp + HID);
  float ss = q[0] * q[0] + q[1] * q[1];
#pragma unroll
  for (int off = 32; off; off >>= 1) ss += __shfl_xor(ss, off);
  float inv = rsqrtf(ss);
  half2t qh = {(_Float16)q[0], (_Float16)q[1]};
  half2t kh = {(_Float16)k[0], (_Float16)k[1]};
  half2t qnh = {(_Float16)(q[0] * inv), (_Float16)(q[1] * inv)};
  *(half2t*)(q16 + (size_t)rid * DIM + lane * 2) = qh;
  *(half2t*)(k16 + (size_t)rid * DIM + lane * 2) = kh;
  *(half2t*)(qn16 + (size_t)rid * DIM + lane * 2) = qnh;
}

// ---------------------------------------------------------------------------
// Candidate filter: sim = Qn @ Kn^T, f16 MFMA, threshold 0.249 (margin 1e-3).
// K-fragments in registers (kn16 read exactly once); Q staged in LDS.
// Filter only PROPOSES; select_topk re-scores in double -> flip-tolerant.
// ---------------------------------------------------------------------------
__global__ __launch_bounds__(256) void sim_cand(const _Float16* __restrict__ qn16,
                                                const _Float16* __restrict__ kn16,
                                                int* __restrict__ cnt,
                                                int* __restrict__ cidx) {
  __shared__ __align__(16) _Float16 Qs[64][132];
  int b = blockIdx.x;
  int h = b & 15, cblk = b >> 4;
  int t = threadIdx.x, lane = t & 63, w = t >> 6;
  int quad = lane >> 4, rr = lane & 15;

  half8 bf[2][4];
  {
    const _Float16* kb = kn16 + ((size_t)(h * SCACHE + cblk * 128 + w * 32)) * DIM;
#pragma unroll
    for (int jn = 0; jn < 2; ++jn)
#pragma unroll
      for (int ks = 0; ks < 4; ++ks)
        bf[jn][ks] = *(const half8*)(kb + (size_t)(jn * 16 + rr) * DIM + ks * 32 + quad * 8);
  }

  for (int qt = 0; qt < 8; ++qt) {
    __syncthreads();
    const _Float16* qb = qn16 + ((size_t)(h * SEQ + qt * 64)) * DIM;
#pragma unroll
    for (int i = 0; i < 4; ++i) {
      int f = t + 256 * i;
      int row = f >> 4, c8 = (f & 15) * 8;
      *(uint4*)&Qs[row][c8] = *(const uint4*)(qb + (size_t)row * DIM + c8);
    }
    __syncthreads();

    f32x4 acc[4][2] = {};
#pragma unroll
    for (int ks = 0; ks < 4; ++ks) {
      int ko = ks * 32 + quad * 8;
      half8 af[4];
#pragma unroll
      for (int i = 0; i < 4; ++i) af[i] = *(const half8*)&Qs[i * 16 + rr][ko];
#pragma unroll
      for (int i = 0; i < 4; ++i)
#pragma unroll
        for (int j = 0; j < 2; ++j)
          acc[i][j] = __builtin_amdgcn_mfma_f32_16x16x32_f16(af[i], bf[j][ks], acc[i][j], 0, 0, 0);
    }
    int qrow_base = qt * 64 + (quad << 2);
    int key_base = cblk * 128 + w * 32 + rr;
#pragma unroll
    for (int i = 0; i < 4; ++i)
#pragma unroll
      for (int j = 0; j < 2; ++j)
#pragma unroll
        for (int r = 0; r < 4; ++r) {
          float v = acc[i][j][r];
          if (v > 0.249f) {
            int q = qrow_base + i * 16 + r;
            int rowid = h * SEQ + q;
            int pos = atomicAdd(&cnt[rowid], 1);
            if (pos < CAP) cidx[rowid * CAP + pos] = key_base + j * 16;
          }
        }
  }
}

// ---------------------------------------------------------------------------
// Candidate-parallel exact re-score + top-16 membership (double precision).
// Reads hi-precision q straight from qkv (stride 3*HID).
// ---------------------------------------------------------------------------
__global__ __launch_bounds__(256) void select_topk(const int* __restrict__ cnt,
                                                   const int* __restrict__ cidx,
                                                   const float* __restrict__ qkv,
                                                   const float* __restrict__ kcache,
                                                   const double* __restrict__ kninv,
                                                   int* __restrict__ sel_idx,
                                                   float* __restrict__ sel_score) {
  int w = threadIdx.x >> 6, lane = threadIdx.x & 63;
  int rowid = blockIdx.x * 4 + w;
  int h = rowid >> 9, s = rowid & 511;
  const float* qp = qkv + (size_t)s * (3 * HID) + h * DIM;

  f32x2 qv2 = *(const f32x2*)(qp + lane * 2);
  double qs = (double)qv2[0] * qv2[0] + (double)qv2[1] * qv2[1];
#pragma unroll
  for (int off = 32; off; off >>= 1) qs += __shfl_xor(qs, off);
  double thr = 0.25 * sqrt(qs);

  int n = min(cnt[rowid], CAP);
  int idx = 0x7fffffff;
  double r = -1e300, d = 0.0;
  if (lane < n) {
    idx = cidx[rowid * CAP + lane];
    const float* kp = kcache + ((size_t)(h * SCACHE + idx)) * DIM;
    double d0 = 0.0, d1 = 0.0;
#pragma unroll
    for (int j = 0; j < DIM; j += 8) {
      f32x4 ka = *(const f32x4*)(kp + j);
      f32x4 kb = *(const f32x4*)(kp + j + 4);
      f32x4 qa = *(const f32x4*)(qp + j);
      f32x4 qb = *(const f32x4*)(qp + j + 4);
      d0 = fma((double)qa[0], (double)ka[0], d0);
      d1 = fma((double)qa[1], (double)ka[1], d1);
      d0 = fma((double)qa[2], (double)ka[2], d0);
      d1 = fma((double)qa[3], (double)ka[3], d1);
      d0 = fma((double)qb[0], (double)kb[0], d0);
      d1 = fma((double)qb[1], (double)kb[1], d1);
      d0 = fma((double)qb[2], (double)kb[2], d0);
      d1 = fma((double)qb[3], (double)kb[3], d1);
    }
    d = d0 + d1;
    r = d * kninv[h * SCACHE + idx];
  }

  int rank = 0;
  for (int j = 0; j < n; ++j) {
    double rj = __shfl(r, j);
    int ij = __shfl(idx, j);
    if (rj > r || (rj == r && ij < idx)) ++rank;
  }
  bool sel = (lane < n) && (rank < 16) && (r > thr);
  unsigned long long m = __ballot(sel);
  int nsel = __popcll(m);
  if (sel) {
    int pos = __popcll(m & ((1ull << lane) - 1));
    sel_idx[rowid * 16 + pos] = idx;
    sel_score[rowid * 16 + pos] = (float)(d * (double)SCALE);
  }
  if (lane >= nsel && lane < 16) {
    sel_idx[rowid * 16 + lane] = 0;
    sel_score[rowid * 16 + lane] = NEG_INF;
  }
}

// ---------------------------------------------------------------------------
// Flash-style local attention, stage 1.
// ---------------------------------------------------------------------------
__global__ __launch_bounds__(256) void attn_part(const float* __restrict__ qkv,
                                                 const _Float16* __restrict__ q16,
                                                 const _Float16* __restrict__ k16,
                                                 const float* __restrict__ bias,
                                                 float* __restrict__ part_m,
                                                 float* __restrict__ part_l,
                                                 float* __restrict__ part_o) {
  __shared__ __align__(16) _Float16 Vs[128][136];  // V^T: [dim][key]
  __shared__ __align__(16) _Float16 Ps[16][136];   // P:   [q][key]
  __shared__ float mred[16][4], lred[16][4];

  int pb = blockIdx.x;
  int tt = pb % 80, h = pb / 80;
  int qb, cb;
  if (tt < 8)       { qb = tt;                cb = 0; }
  else if (tt < 24) { int u = tt - 8;  qb = 8 + (u >> 1); cb = u & 1; }
  else if (tt < 48) { int u = tt - 24; int q3 = u / 3; qb = 16 + q3; cb = u - q3 * 3; }
  else              { int u = tt - 48; qb = 24 + (u >> 2); cb = u & 3; }
  int q0 = qb * 16, kc0 = cb * 128;

  int t = threadIdx.x, lane = t & 63, w = t >> 6;
  int quad = lane >> 4, col = lane & 15;

  const float* vbase = qkv + 2 * HID + h * DIM;
#pragma unroll
  for (int i = 0; i < 16; ++i) {
    int idx = t + 256 * i;
    int key = idx & 127, dg = idx >> 7;
    f32x4 vv = *(const f32x4*)(vbase + (size_t)(kc0 + key) * (3 * HID) + dg * 4);
#pragma unroll
    for (int e = 0; e < 4; ++e) Vs[dg * 4 + e][key] = (_Float16)vv[e];
  }

  const _Float16* qbp = q16 + ((size_t)(h * SEQ + q0)) * DIM;
  half8 af[4];
#pragma unroll
  for (int ks = 0; ks < 4; ++ks)
    af[ks] = *(const half8*)(qbp + (size_t)col * DIM + ks * 32 + quad * 8);

  f32x4 acc[2] = {};
#pragma unroll
  for (int jn = 0; jn < 2; ++jn) {
    const _Float16* kp = k16 + ((size_t)(h * SEQ + kc0 + w * 32 + jn * 16 + col)) * DIM;
#pragma unroll
    for (int ks = 0; ks < 4; ++ks) {
      half8 bf = *(const half8*)(kp + ks * 32 + quad * 8);
      acc[jn] = __builtin_amdgcn_mfma_f32_16x16x32_f16(af[ks], bf, acc[jn], 0, 0, 0);
    }
  }
  float s[2][4];
#pragma unroll
  for (int jn = 0; jn < 2; ++jn) {
    int keyg = kc0 + w * 32 + jn * 16 + col;
#pragma unroll
    for (int r = 0; r < 4; ++r) {
      int qrow = q0 + quad * 4 + r;
      float sv = NEG_INF;
      if (keyg <= qrow)
        sv = acc[jn][r] * SCALE + bias[((size_t)h * SEQ + qrow) * SEQ + keyg];
      s[jn][r] = sv;
    }
  }

  float mw[4];
#pragma unroll
  for (int r = 0; r < 4; ++r) {
    float m = fmaxf(s[0][r], s[1][r]);
#pragma unroll
    for (int off = 1; off < 16; off <<= 1) m = fmaxf(m, __shfl_xor(m, off));
    mw[r] = m;
  }
  if (col == 0)
#pragma unroll
    for (int r = 0; r < 4; ++r) mred[quad * 4 + r][w] = mw[r];
  __syncthreads();

  float M[4];
#pragma unroll
  for (int r = 0; r < 4; ++r) {
    int row = quad * 4 + r;
    float m = fmaxf(fmaxf(mred[row][0], mred[row][1]),
                    fmaxf(mred[row][2], mred[row][3]));
    M[r] = m;
    float p0 = __expf(s[0][r] - m);
    float p1 = __expf(s[1][r] - m);
    Ps[row][w * 32 + col] = (_Float16)p0;
    Ps[row][w * 32 + 16 + col] = (_Float16)p1;
    float l = p0 + p1;
#pragma unroll
    for (int off = 1; off < 16; off <<= 1) l += __shfl_xor(l, off);
    if (col == 0) lred[row][w] = l;
  }
  if (w == 0 && col == 0)
#pragma unroll
    for (int r = 0; r < 4; ++r) part_m[pb * 16 + quad * 4 + r] = M[r];
  __syncthreads();

  f32x4 o[2] = {};
#pragma unroll
  for (int jn = 0; jn < 2; ++jn) {
#pragma unroll
    for (int ks = 0; ks < 4; ++ks) {
      half8 a = *(const half8*)&Ps[col][ks * 32 + quad * 8];
      half8 bv = *(const half8*)&Vs[w * 32 + jn * 16 + col][ks * 32 + quad * 8];
      o[jn] = __builtin_amdgcn_mfma_f32_16x16x32_f16(a, bv, o[jn], 0, 0, 0);
    }
  }
#pragma unroll
  for (int jn = 0; jn < 2; ++jn)
#pragma unroll
    for (int r = 0; r < 4; ++r)
      part_o[((size_t)pb * 16 + quad * 4 + r) * 128 + w * 32 + jn * 16 + col] = o[jn][r];
  if (t < 16)
    part_l[pb * 16 + t] = lred[t][0] + lred[t][1] + lred[t][2] + lred[t][3];
}

// ---------------------------------------------------------------------------
// Flash merge: wave per (h,q) row.
// ---------------------------------------------------------------------------
__global__ __launch_bounds__(256) void attn_merge(const float* __restrict__ part_m,
                                                  const float* __restrict__ part_l,
                                                  const float* __restrict__ part_o,
                                                  const int* __restrict__ sel_idx,
                                                  const float* __restrict__ sel_score,
                                                  const float* __restrict__ vcache,
                                                  float* __restrict__ ctx) {
  int w = threadIdx.x >> 6, lane = threadIdx.x & 63;
  int row = blockIdx.x * 4 + w;
  int h = row >> 9, q = row & 511;
  int qb = q >> 4, r = q & 15;
  int base = (qb < 8) ? qb
           : (qb < 16) ? 8 + 2 * (qb - 8)
           : (qb < 24) ? 24 + 3 * (qb - 16)
                       : 48 + 4 * (qb - 24);
  int ncb = (qb >> 3) + 1;
  int pb0 = h * 80 + base;

  float scv[16], mc = NEG_INF;
#pragma unroll
  for (int j = 0; j < 16; ++j) {
    scv[j] = sel_score[row * 16 + j];
    mc = fmaxf(mc, scv[j]);
  }
  float mi[4];
  float M = mc;
  for (int i = 0; i < ncb; ++i) {
    mi[i] = part_m[(pb0 + i) * 16 + r];
    M = fmaxf(M, mi[i]);
  }
  f32x2 O = {0.f, 0.f};
  float L = 0.f;
  for (int i = 0; i < ncb; ++i) {
    float sc = __expf(mi[i] - M);
    f32x2 ov = *(const f32x2*)(part_o + ((size_t)(pb0 + i) * 16 + r) * 128 + lane * 2);
    O += ov * sc;
    L += part_l[(pb0 + i) * 16 + r] * sc;
  }
#pragma unroll
  for (int j = 0; j < 16; ++j) {
    if (scv[j] > NEG_INF) {
      float wv = __expf(scv[j] - M);
      int idx = sel_idx[row * 16 + j];
      f32x2 v = *(const f32x2*)(vcache + ((size_t)(h * SCACHE + idx)) * DIM + lane * 2);
      O += v * wv;
      L += wv;
    }
  }
  f32x2 res = O * (1.f / L);
  *(f32x2*)(ctx + (size_t)q * HID + h * DIM + lane * 2) = res;
}

// ---------------------------------------------------------------------------
extern "C" void kernel_launch(void* const* d_in, const int* in_sizes, int n_in,
                              void* d_out, int out_size, void* d_ws, size_t ws_size,
                              hipStream_t stream) {
  const float* hidden = (const float*)d_in[0];
  const float* Wqkv   = (const float*)d_in[1];
  const float* Wout   = (const float*)d_in[2];
  const float* kcache = (const float*)d_in[3];
  const float* vcache = (const float*)d_in[4];
  const float* bias   = (const float*)d_in[5];

  char* ws = (char*)d_ws;
  size_t off = 0;
  float*    qkv   = (float*)(ws + off);    off += (size_t)SEQ * 3 * HID * 4;
  _Float16* q16   = (_Float16*)(ws + off); off += (size_t)NHEAD * SEQ * DIM * 2;
  _Float16* k16   = (_Float16*)(ws + off); off += (size_t)NHEAD * SEQ * DIM * 2;
  _Float16* qn16  = (_Float16*)(ws + off); off += (size_t)NHEAD * SEQ * DIM * 2;
  _Float16* kn16  = (_Float16*)(ws + off); off += (size_t)NHEAD * SCACHE * DIM * 2;
  double*   kninv = (double*)(ws + off);   off += (size_t)NHEAD * SCACHE * 8;
  int*      ccnt  = (int*)(ws + off);      off += (size_t)NHEAD * SEQ * 4;
  int*      cidx  = (int*)(ws + off);      off += (size_t)NHEAD * SEQ * CAP * 4;
  int*      selidx  = (int*)(ws + off);    off += (size_t)NHEAD * SEQ * 16 * 4;
  float*    selsc   = (float*)(ws + off);  off += (size_t)NHEAD * SEQ * 16 * 4;
  float*    ctx   = (float*)(ws + off);    off += (size_t)SEQ * HID * 4;
  float*    pm    = (float*)(ws + off);    off += (size_t)1280 * 16 * 4;
  float*    pl    = (float*)(ws + off);    off += (size_t)1280 * 16 * 4;
  float*    po    = (float*)(ws + off);    off += (size_t)1280 * 16 * 128 * 4;

  hipMemsetAsync(ccnt, 0, (size_t)NHEAD * SEQ * 4, stream);
  cache_norm<<<dim3(NHEAD * SCACHE / 4), dim3(256), 0, stream>>>(kcache, kn16, kninv);
  // k/v thirds (cols 2048..6143 of Wqkv) straight into qkv at stride 6144
  gemm_xwT<<<dim3(4 * 32), dim3(256), 0, stream>>>(hidden, Wqkv + (size_t)2048 * 2048,
                                                   qkv + 2048, 3 * HID, 2048, 32);
  // q third, bit-identical chain, 256 blocks
  gemm_q_hi<<<dim3(256), dim3(256), 0, stream>>>(hidden, Wqkv, qkv);
  prep_local<<<dim3(NHEAD * SEQ / 4), dim3(256), 0, stream>>>(qkv, q16, k16, qn16);
  sim_cand<<<dim3(NHEAD * 64), dim3(256), 0, stream>>>(qn16, kn16, ccnt, cidx);
  select_topk<<<dim3(NHEAD * SEQ / 4), dim3(256), 0, stream>>>(ccnt, cidx, qkv, kcache,
                                                               kninv, selidx, selsc);
  attn_part<<<dim3(16 * 80), dim3(256), 0, stream>>>(qkv, q16, k16, bias, pm, pl, po);
  attn_merge<<<dim3(NHEAD * SEQ / 4), dim3(256), 0, stream>>>(pm, pl, po, selidx, selsc,
                                                              vcache, ctx);
  gemm_xwT<<<dim3(4 * 16), dim3(256), 0, stream>>>(ctx, Wout, (float*)d_out, 2048, 2048, 16);
}

// Round 7
// 495.798 us; speedup vs baseline: 1.4990x; 1.1639x over previous
//
#include <hip/hip_runtime.h>

typedef _Float16 half8 __attribute__((ext_vector_type(8)));
typedef _Float16 half4 __attribute__((ext_vector_type(4)));
typedef _Float16 half2t __attribute__((ext_vector_type(2)));
typedef float f32x4 __attribute__((ext_vector_type(4)));
typedef float f32x2 __attribute__((ext_vector_type(2)));

#define NHEAD 16
#define SEQ 512
#define DIM 128
#define HID 2048
#define SCACHE 8192
#define CAP 64
#define SCALE 0.08838834764831845f   // 1/sqrt(128)
#define NEG_INF (-__builtin_inff())

// ---------------------------------------------------------------------------
// Split-K tile GEMM: Cpart[kblk] += A[M,K] @ B[N,K]^T slice (f16 MFMA).
// 128x128 tiles, BK=64. Grid = mblks * gridN * kslices. N = gridN*128.
// Used for k/v and out-proj (smooth outputs -> split-K re-ordering is legal;
// q-third must NOT go through this: its bits decide selection).
// ---------------------------------------------------------------------------
__global__ __launch_bounds__(256) void gemm_xwT(const float* __restrict__ A,
                                                const float* __restrict__ B,
                                                float* __restrict__ Cpart,
                                                int K, int gridN, int kslices) {
  __shared__ __align__(16) _Float16 As[128][84];
  __shared__ __align__(16) _Float16 Bs[128][84];
  int b = blockIdx.x;
  int kblk = b % kslices;
  int nm = b / kslices;
  int nblk = nm % gridN, mblk = nm / gridN;
  int N = gridN * 128;
  int kchunk = K / kslices;
  int t = threadIdx.x;
  int lane = t & 63, wid = t >> 6;
  int wm = (wid >> 1) * 64, wn = (wid & 1) * 64;
  f32x4 acc[4][4] = {};
  const float* Ab = A + (size_t)mblk * 128 * K;
  const float* Bb = B + (size_t)nblk * 128 * K;
  int rowS = t >> 4, c4 = (t & 15) * 4;

  for (int k0 = kblk * kchunk; k0 < kblk * kchunk + kchunk; k0 += 64) {
#pragma unroll
    for (int i = 0; i < 8; ++i) {
      int row = rowS + 16 * i;
      float4 av = *(const float4*)(Ab + (size_t)row * K + k0 + c4);
      float4 bv = *(const float4*)(Bb + (size_t)row * K + k0 + c4);
      half4 ah = {(_Float16)av.x, (_Float16)av.y, (_Float16)av.z, (_Float16)av.w};
      half4 bh = {(_Float16)bv.x, (_Float16)bv.y, (_Float16)bv.z, (_Float16)bv.w};
      *(half4*)&As[row][c4] = ah;
      *(half4*)&Bs[row][c4] = bh;
    }
    __syncthreads();
#pragma unroll
    for (int ks = 0; ks < 2; ++ks) {
      int ko = ks * 32 + (lane >> 4) * 8;
      int rr = lane & 15;
      half8 af[4], bf[4];
#pragma unroll
      for (int i = 0; i < 4; ++i) af[i] = *(const half8*)&As[wm + i * 16 + rr][ko];
#pragma unroll
      for (int j = 0; j < 4; ++j) bf[j] = *(const half8*)&Bs[wn + j * 16 + rr][ko];
#pragma unroll
      for (int i = 0; i < 4; ++i)
#pragma unroll
        for (int j = 0; j < 4; ++j)
          acc[i][j] = __builtin_amdgcn_mfma_f32_16x16x32_f16(af[i], bf[j], acc[i][j], 0, 0, 0);
    }
    __syncthreads();
  }
  float* Cp = Cpart + (size_t)kblk * ((size_t)gridN * 128) * 512;  // M=512 rows/slice
  int cR = (lane >> 4) * 4, cC = lane & 15;
#pragma unroll
  for (int i = 0; i < 4; ++i)
#pragma unroll
    for (int j = 0; j < 4; ++j) {
      int row = mblk * 128 + wm + i * 16 + cR;
      int col = nblk * 128 + wn + j * 16 + cC;
#pragma unroll
      for (int r = 0; r < 4; ++r)
        Cp[(size_t)(row + r) * N + col] = acc[i][j][r];
    }
}

// Deterministic split-K reduce. dst[row*dstride + col] = sum_p part[p][row][col]
// ncol = partial row width; slice = 512*ncol elements.
__global__ __launch_bounds__(256) void reduce_k(const float* __restrict__ part,
                                                float* __restrict__ dst,
                                                int kslices, int ncol, int dstride) {
  size_t e = ((size_t)blockIdx.x * 256 + threadIdx.x) * 4;
  size_t slice = (size_t)512 * ncol;
  f32x4 s = *(const f32x4*)(part + e);
  for (int p = 1; p < kslices; ++p)
    s += *(const f32x4*)(part + (size_t)p * slice + e);
  size_t row = e / ncol;
  int col = (int)(e % ncol);
  *(f32x4*)(dst + row * dstride + col) = s;
}

// ---------------------------------------------------------------------------
// q-third at fp32 accuracy via 3-term f16 split MFMA. BIT-IDENTICAL chain
// (K 0..2048 step 32, 3-MFMA order, acc=0) — selection depends on these bits.
// 64x64 tiles -> 256 blocks. Writes into qkv cols 0..2047 (stride 6144).
// ---------------------------------------------------------------------------
__global__ __launch_bounds__(256) void gemm_q_hi(const float* __restrict__ A,
                                                 const float* __restrict__ B,
                                                 float* __restrict__ C) {
  __shared__ __align__(16) _Float16 Ah[64][40], Al[64][40];
  __shared__ __align__(16) _Float16 Bh[64][40], Bl[64][40];
  int b = blockIdx.x;
  int nblk = b & 31, mblk = b >> 5;
  int t = threadIdx.x, lane = t & 63, wid = t >> 6;
  int wm = (wid >> 1) * 32, wn = (wid & 1) * 32;
  int quad = lane >> 4, rr = lane & 15;
  f32x4 acc[2][2] = {};
  const float* Ab = A + (size_t)mblk * 64 * 2048;
  const float* Bb = B + (size_t)nblk * 64 * 2048;
  int rowS = t >> 2, cS = (t & 3) * 8;

  for (int k0 = 0; k0 < 2048; k0 += 32) {
#pragma unroll
    for (int half = 0; half < 2; ++half) {
      int c = cS + half * 4;
      float4 av = *(const float4*)(Ab + (size_t)rowS * 2048 + k0 + c);
      float4 bv = *(const float4*)(Bb + (size_t)rowS * 2048 + k0 + c);
      half4 ah = {(_Float16)av.x, (_Float16)av.y, (_Float16)av.z, (_Float16)av.w};
      half4 bh = {(_Float16)bv.x, (_Float16)bv.y, (_Float16)bv.z, (_Float16)bv.w};
      half4 al = {(_Float16)(av.x - (float)ah.x), (_Float16)(av.y - (float)ah.y),
                  (_Float16)(av.z - (float)ah.z), (_Float16)(av.w - (float)ah.w)};
      half4 bl = {(_Float16)(bv.x - (float)bh.x), (_Float16)(bv.y - (float)bh.y),
                  (_Float16)(bv.z - (float)bh.z), (_Float16)(bv.w - (float)bh.w)};
      *(half4*)&Ah[rowS][c] = ah;
      *(half4*)&Al[rowS][c] = al;
      *(half4*)&Bh[rowS][c] = bh;
      *(half4*)&Bl[rowS][c] = bl;
    }
    __syncthreads();
    int ko = quad * 8;
    half8 afh[2], afl[2], bfh[2], bfl[2];
#pragma unroll
    for (int i = 0; i < 2; ++i) {
      afh[i] = *(const half8*)&Ah[wm + i * 16 + rr][ko];
      afl[i] = *(const half8*)&Al[wm + i * 16 + rr][ko];
      bfh[i] = *(const half8*)&Bh[wn + i * 16 + rr][ko];
      bfl[i] = *(const half8*)&Bl[wn + i * 16 + rr][ko];
    }
#pragma unroll
    for (int i = 0; i < 2; ++i)
#pragma unroll
      for (int j = 0; j < 2; ++j) {
        acc[i][j] = __builtin_amdgcn_mfma_f32_16x16x32_f16(afl[i], bfh[j], acc[i][j], 0, 0, 0);
        acc[i][j] = __builtin_amdgcn_mfma_f32_16x16x32_f16(afh[i], bfl[j], acc[i][j], 0, 0, 0);
        acc[i][j] = __builtin_amdgcn_mfma_f32_16x16x32_f16(afh[i], bfh[j], acc[i][j], 0, 0, 0);
      }
    __syncthreads();
  }
  int cR = quad * 4;
#pragma unroll
  for (int i = 0; i < 2; ++i)
#pragma unroll
    for (int j = 0; j < 2; ++j) {
      int row = mblk * 64 + wm + i * 16 + cR;
      int col = nblk * 64 + wn + j * 16 + rr;
#pragma unroll
      for (int r = 0; r < 4; ++r)
        C[(size_t)(row + r) * (3 * HID) + col] = acc[i][j][r];
    }
}

// ---------------------------------------------------------------------------
// k_cache: f16 normalized copy (filter) + double 1/||k|| (exact re-scoring).
// ---------------------------------------------------------------------------
__global__ __launch_bounds__(256) void cache_norm(const float* __restrict__ kc,
                                                  _Float16* __restrict__ kn16,
                                                  double* __restrict__ kninv) {
  int w = threadIdx.x >> 6, lane = threadIdx.x & 63;
  int row = blockIdx.x * 4 + w;
  f32x2 v = *(const f32x2*)(kc + (size_t)row * DIM + lane * 2);
  double s = (double)v[0] * v[0] + (double)v[1] * v[1];
#pragma unroll
  for (int off = 32; off; off >>= 1) s += __shfl_xor(s, off);
  float inv = rsqrtf((float)s);
  half2t o = {(_Float16)(v[0] * inv), (_Float16)(v[1] * inv)};
  *(half2t*)(kn16 + (size_t)row * DIM + lane * 2) = o;
  if (lane == 0) kninv[row] = 1.0 / sqrt(s);
}

// ---------------------------------------------------------------------------
// From qkv: per-head f16 q, k_local, normalized q. Wave per (h,s).
// ---------------------------------------------------------------------------
__global__ __launch_bounds__(256) void prep_local(const float* __restrict__ qkv,
                                                  _Float16* __restrict__ q16,
                                                  _Float16* __restrict__ k16,
                                                  _Float16* __restrict__ qn16) {
  int w = threadIdx.x >> 6, lane = threadIdx.x & 63;
  int rid = blockIdx.x * 4 + w;
  int h = rid >> 9, s = rid & 511;
  const float* qp = qkv + (size_t)s * (3 * HID) + h * DIM + lane * 2;
  f32x2 q = *(const f32x2*)qp;
  f32x2 k = *(const f32x2*)(qp + HID);
  float ss = q[0] * q[0] + q[1] * q[1];
#pragma unroll
  for (int off = 32; off; off >>= 1) ss += __shfl_xor(ss, off);
  float inv = rsqrtf(ss);
  half2t qh = {(_Float16)q[0], (_Float16)q[1]};
  half2t kh = {(_Float16)k[0], (_Float16)k[1]};
  half2t qnh = {(_Float16)(q[0] * inv), (_Float16)(q[1] * inv)};
  *(half2t*)(q16 + (size_t)rid * DIM + lane * 2) = qh;
  *(half2t*)(k16 + (size_t)rid * DIM + lane * 2) = kh;
  *(half2t*)(qn16 + (size_t)rid * DIM + lane * 2) = qnh;
}

// ---------------------------------------------------------------------------
// Candidate filter: sim = Qn @ Kn^T, f16 MFMA, threshold 0.249 (margin 1e-3).
// K-fragments in registers (kn16 read exactly once); Q staged in LDS.
// ---------------------------------------------------------------------------
__global__ __launch_bounds__(256) void sim_cand(const _Float16* __restrict__ qn16,
                                                const _Float16* __restrict__ kn16,
                                                int* __restrict__ cnt,
                                                int* __restrict__ cidx) {
  __shared__ __align__(16) _Float16 Qs[64][132];
  int b = blockIdx.x;
  int h = b & 15, cblk = b >> 4;
  int t = threadIdx.x, lane = t & 63, w = t >> 6;
  int quad = lane >> 4, rr = lane & 15;

  half8 bf[2][4];
  {
    const _Float16* kb = kn16 + ((size_t)(h * SCACHE + cblk * 128 + w * 32)) * DIM;
#pragma unroll
    for (int jn = 0; jn < 2; ++jn)
#pragma unroll
      for (int ks = 0; ks < 4; ++ks)
        bf[jn][ks] = *(const half8*)(kb + (size_t)(jn * 16 + rr) * DIM + ks * 32 + quad * 8);
  }

  for (int qt = 0; qt < 8; ++qt) {
    __syncthreads();
    const _Float16* qb = qn16 + ((size_t)(h * SEQ + qt * 64)) * DIM;
#pragma unroll
    for (int i = 0; i < 4; ++i) {
      int f = t + 256 * i;
      int row = f >> 4, c8 = (f & 15) * 8;
      *(uint4*)&Qs[row][c8] = *(const uint4*)(qb + (size_t)row * DIM + c8);
    }
    __syncthreads();

    f32x4 acc[4][2] = {};
#pragma unroll
    for (int ks = 0; ks < 4; ++ks) {
      int ko = ks * 32 + quad * 8;
      half8 af[4];
#pragma unroll
      for (int i = 0; i < 4; ++i) af[i] = *(const half8*)&Qs[i * 16 + rr][ko];
#pragma unroll
      for (int i = 0; i < 4; ++i)
#pragma unroll
        for (int j = 0; j < 2; ++j)
          acc[i][j] = __builtin_amdgcn_mfma_f32_16x16x32_f16(af[i], bf[j][ks], acc[i][j], 0, 0, 0);
    }
    int qrow_base = qt * 64 + (quad << 2);
    int key_base = cblk * 128 + w * 32 + rr;
#pragma unroll
    for (int i = 0; i < 4; ++i)
#pragma unroll
      for (int j = 0; j < 2; ++j)
#pragma unroll
        for (int r = 0; r < 4; ++r) {
          float v = acc[i][j][r];
          if (v > 0.249f) {
            int q = qrow_base + i * 16 + r;
            int rowid = h * SEQ + q;
            int pos = atomicAdd(&cnt[rowid], 1);
            if (pos < CAP) cidx[rowid * CAP + pos] = key_base + j * 16;
          }
        }
  }
}

// ---------------------------------------------------------------------------
// Candidate-parallel exact re-score + top-16 membership (double precision).
// ---------------------------------------------------------------------------
__global__ __launch_bounds__(256) void select_topk(const int* __restrict__ cnt,
                                                   const int* __restrict__ cidx,
                                                   const float* __restrict__ qkv,
                                                   const float* __restrict__ kcache,
                                                   const double* __restrict__ kninv,
                                                   int* __restrict__ sel_idx,
                                                   float* __restrict__ sel_score) {
  int w = threadIdx.x >> 6, lane = threadIdx.x & 63;
  int rowid = blockIdx.x * 4 + w;
  int h = rowid >> 9, s = rowid & 511;
  const float* qp = qkv + (size_t)s * (3 * HID) + h * DIM;

  f32x2 qv2 = *(const f32x2*)(qp + lane * 2);
  double qs = (double)qv2[0] * qv2[0] + (double)qv2[1] * qv2[1];
#pragma unroll
  for (int off = 32; off; off >>= 1) qs += __shfl_xor(qs, off);
  double thr = 0.25 * sqrt(qs);

  int n = min(cnt[rowid], CAP);
  int idx = 0x7fffffff;
  double r = -1e300, d = 0.0;
  if (lane < n) {
    idx = cidx[rowid * CAP + lane];
    const float* kp = kcache + ((size_t)(h * SCACHE + idx)) * DIM;
    double d0 = 0.0, d1 = 0.0;
#pragma unroll
    for (int j = 0; j < DIM; j += 8) {
      f32x4 ka = *(const f32x4*)(kp + j);
      f32x4 kb = *(const f32x4*)(kp + j + 4);
      f32x4 qa = *(const f32x4*)(qp + j);
      f32x4 qb = *(const f32x4*)(qp + j + 4);
      d0 = fma((double)qa[0], (double)ka[0], d0);
      d1 = fma((double)qa[1], (double)ka[1], d1);
      d0 = fma((double)qa[2], (double)ka[2], d0);
      d1 = fma((double)qa[3], (double)ka[3], d1);
      d0 = fma((double)qb[0], (double)kb[0], d0);
      d1 = fma((double)qb[1], (double)kb[1], d1);
      d0 = fma((double)qb[2], (double)kb[2], d0);
      d1 = fma((double)qb[3], (double)kb[3], d1);
    }
    d = d0 + d1;
    r = d * kninv[h * SCACHE + idx];
  }

  int rank = 0;
  for (int j = 0; j < n; ++j) {
    double rj = __shfl(r, j);
    int ij = __shfl(idx, j);
    if (rj > r || (rj == r && ij < idx)) ++rank;
  }
  bool sel = (lane < n) && (rank < 16) && (r > thr);
  unsigned long long m = __ballot(sel);
  int nsel = __popcll(m);
  if (sel) {
    int pos = __popcll(m & ((1ull << lane) - 1));
    sel_idx[rowid * 16 + pos] = idx;
    sel_score[rowid * 16 + pos] = (float)(d * (double)SCALE);
  }
  if (lane >= nsel && lane < 16) {
    sel_idx[rowid * 16 + lane] = 0;
    sel_score[rowid * 16 + lane] = NEG_INF;
  }
}

// ---------------------------------------------------------------------------
// Flash-style local attention, stage 1.
// ---------------------------------------------------------------------------
__global__ __launch_bounds__(256) void attn_part(const float* __restrict__ qkv,
                                                 const _Float16* __restrict__ q16,
                                                 const _Float16* __restrict__ k16,
                                                 const float* __restrict__ bias,
                                                 float* __restrict__ part_m,
                                                 float* __restrict__ part_l,
                                                 float* __restrict__ part_o) {
  __shared__ __align__(16) _Float16 Vs[128][136];  // V^T: [dim][key]
  __shared__ __align__(16) _Float16 Ps[16][136];   // P:   [q][key]
  __shared__ float mred[16][4], lred[16][4];

  int pb = blockIdx.x;
  int tt = pb % 80, h = pb / 80;
  int qb, cb;
  if (tt < 8)       { qb = tt;                cb = 0; }
  else if (tt < 24) { int u = tt - 8;  qb = 8 + (u >> 1); cb = u & 1; }
  else if (tt < 48) { int u = tt - 24; int q3 = u / 3; qb = 16 + q3; cb = u - q3 * 3; }
  else              { int u = tt - 48; qb = 24 + (u >> 2); cb = u & 3; }
  int q0 = qb * 16, kc0 = cb * 128;

  int t = threadIdx.x, lane = t & 63, w = t >> 6;
  int quad = lane >> 4, col = lane & 15;

  const float* vbase = qkv + 2 * HID + h * DIM;
#pragma unroll
  for (int i = 0; i < 16; ++i) {
    int idx = t + 256 * i;
    int key = idx & 127, dg = idx >> 7;
    f32x4 vv = *(const f32x4*)(vbase + (size_t)(kc0 + key) * (3 * HID) + dg * 4);
#pragma unroll
    for (int e = 0; e < 4; ++e) Vs[dg * 4 + e][key] = (_Float16)vv[e];
  }

  const _Float16* qbp = q16 + ((size_t)(h * SEQ + q0)) * DIM;
  half8 af[4];
#pragma unroll
  for (int ks = 0; ks < 4; ++ks)
    af[ks] = *(const half8*)(qbp + (size_t)col * DIM + ks * 32 + quad * 8);

  f32x4 acc[2] = {};
#pragma unroll
  for (int jn = 0; jn < 2; ++jn) {
    const _Float16* kp = k16 + ((size_t)(h * SEQ + kc0 + w * 32 + jn * 16 + col)) * DIM;
#pragma unroll
    for (int ks = 0; ks < 4; ++ks) {
      half8 bf = *(const half8*)(kp + ks * 32 + quad * 8);
      acc[jn] = __builtin_amdgcn_mfma_f32_16x16x32_f16(af[ks], bf, acc[jn], 0, 0, 0);
    }
  }
  float s[2][4];
#pragma unroll
  for (int jn = 0; jn < 2; ++jn) {
    int keyg = kc0 + w * 32 + jn * 16 + col;
#pragma unroll
    for (int r = 0; r < 4; ++r) {
      int qrow = q0 + quad * 4 + r;
      float sv = NEG_INF;
      if (keyg <= qrow)
        sv = acc[jn][r] * SCALE + bias[((size_t)h * SEQ + qrow) * SEQ + keyg];
      s[jn][r] = sv;
    }
  }

  float mw[4];
#pragma unroll
  for (int r = 0; r < 4; ++r) {
    float m = fmaxf(s[0][r], s[1][r]);
#pragma unroll
    for (int off = 1; off < 16; off <<= 1) m = fmaxf(m, __shfl_xor(m, off));
    mw[r] = m;
  }
  if (col == 0)
#pragma unroll
    for (int r = 0; r < 4; ++r) mred[quad * 4 + r][w] = mw[r];
  __syncthreads();

  float M[4];
#pragma unroll
  for (int r = 0; r < 4; ++r) {
    int row = quad * 4 + r;
    float m = fmaxf(fmaxf(mred[row][0], mred[row][1]),
                    fmaxf(mred[row][2], mred[row][3]));
    M[r] = m;
    float p0 = __expf(s[0][r] - m);
    float p1 = __expf(s[1][r] - m);
    Ps[row][w * 32 + col] = (_Float16)p0;
    Ps[row][w * 32 + 16 + col] = (_Float16)p1;
    float l = p0 + p1;
#pragma unroll
    for (int off = 1; off < 16; off <<= 1) l += __shfl_xor(l, off);
    if (col == 0) lred[row][w] = l;
  }
  if (w == 0 && col == 0)
#pragma unroll
    for (int r = 0; r < 4; ++r) part_m[pb * 16 + quad * 4 + r] = M[r];
  __syncthreads();

  f32x4 o[2] = {};
#pragma unroll
  for (int jn = 0; jn < 2; ++jn) {
#pragma unroll
    for (int ks = 0; ks < 4; ++ks) {
      half8 a = *(const half8*)&Ps[col][ks * 32 + quad * 8];
      half8 bv = *(const half8*)&Vs[w * 32 + jn * 16 + col][ks * 32 + quad * 8];
      o[jn] = __builtin_amdgcn_mfma_f32_16x16x32_f16(a, bv, o[jn], 0, 0, 0);
    }
  }
#pragma unroll
  for (int jn = 0; jn < 2; ++jn)
#pragma unroll
    for (int r = 0; r < 4; ++r)
      part_o[((size_t)pb * 16 + quad * 4 + r) * 128 + w * 32 + jn * 16 + col] = o[jn][r];
  if (t < 16)
    part_l[pb * 16 + t] = lred[t][0] + lred[t][1] + lred[t][2] + lred[t][3];
}

// ---------------------------------------------------------------------------
// Flash merge: wave per (h,q) row.
// ---------------------------------------------------------------------------
__global__ __launch_bounds__(256) void attn_merge(const float* __restrict__ part_m,
                                                  const float* __restrict__ part_l,
                                                  const float* __restrict__ part_o,
                                                  const int* __restrict__ sel_idx,
                                                  const float* __restrict__ sel_score,
                                                  const float* __restrict__ vcache,
                                                  float* __restrict__ ctx) {
  int w = threadIdx.x >> 6, lane = threadIdx.x & 63;
  int row = blockIdx.x * 4 + w;
  int h = row >> 9, q = row & 511;
  int qb = q >> 4, r = q & 15;
  int base = (qb < 8) ? qb
           : (qb < 16) ? 8 + 2 * (qb - 8)
           : (qb < 24) ? 24 + 3 * (qb - 16)
                       : 48 + 4 * (qb - 24);
  int ncb = (qb >> 3) + 1;
  int pb0 = h * 80 + base;

  float scv[16], mc = NEG_INF;
#pragma unroll
  for (int j = 0; j < 16; ++j) {
    scv[j] = sel_score[row * 16 + j];
    mc = fmaxf(mc, scv[j]);
  }
  float mi[4];
  float M = mc;
  for (int i = 0; i < ncb; ++i) {
    mi[i] = part_m[(pb0 + i) * 16 + r];
    M = fmaxf(M, mi[i]);
  }
  f32x2 O = {0.f, 0.f};
  float L = 0.f;
  for (int i = 0; i < ncb; ++i) {
    float sc = __expf(mi[i] - M);
    f32x2 ov = *(const f32x2*)(part_o + ((size_t)(pb0 + i) * 16 + r) * 128 + lane * 2);
    O += ov * sc;
    L += part_l[(pb0 + i) * 16 + r] * sc;
  }
#pragma unroll
  for (int j = 0; j < 16; ++j) {
    if (scv[j] > NEG_INF) {
      float wv = __expf(scv[j] - M);
      int idx = sel_idx[row * 16 + j];
      f32x2 v = *(const f32x2*)(vcache + ((size_t)(h * SCACHE + idx)) * DIM + lane * 2);
      O += v * wv;
      L += wv;
    }
  }
  f32x2 res = O * (1.f / L);
  *(f32x2*)(ctx + (size_t)q * HID + h * DIM + lane * 2) = res;
}

// ---------------------------------------------------------------------------
extern "C" void kernel_launch(void* const* d_in, const int* in_sizes, int n_in,
                              void* d_out, int out_size, void* d_ws, size_t ws_size,
                              hipStream_t stream) {
  const float* hidden = (const float*)d_in[0];
  const float* Wqkv   = (const float*)d_in[1];
  const float* Wout   = (const float*)d_in[2];
  const float* kcache = (const float*)d_in[3];
  const float* vcache = (const float*)d_in[4];
  const float* bias   = (const float*)d_in[5];

  char* ws = (char*)d_ws;
  size_t off = 0;
  float*    qkv   = (float*)(ws + off);    off += (size_t)SEQ * 3 * HID * 4;
  _Float16* q16   = (_Float16*)(ws + off); off += (size_t)NHEAD * SEQ * DIM * 2;
  _Float16* k16   = (_Float16*)(ws + off); off += (size_t)NHEAD * SEQ * DIM * 2;
  _Float16* qn16  = (_Float16*)(ws + off); off += (size_t)NHEAD * SEQ * DIM * 2;
  _Float16* kn16  = (_Float16*)(ws + off); off += (size_t)NHEAD * SCACHE * DIM * 2;
  double*   kninv = (double*)(ws + off);   off += (size_t)NHEAD * SCACHE * 8;
  int*      ccnt  = (int*)(ws + off);      off += (size_t)NHEAD * SEQ * 4;
  int*      cidx  = (int*)(ws + off);      off += (size_t)NHEAD * SEQ * CAP * 4;
  int*      selidx  = (int*)(ws + off);    off += (size_t)NHEAD * SEQ * 16 * 4;
  float*    selsc   = (float*)(ws + off);  off += (size_t)NHEAD * SEQ * 16 * 4;
  float*    ctx   = (float*)(ws + off);    off += (size_t)SEQ * HID * 4;
  float*    pm    = (float*)(ws + off);    off += (size_t)1280 * 16 * 4;
  float*    pl    = (float*)(ws + off);    off += (size_t)1280 * 16 * 4;
  float*    po    = (float*)(ws + off);    off += (size_t)1280 * 16 * 128 * 4;
  // union region (32 MB): kv split-K partials (lifetime: kv gemm -> kv reduce)
  // then out-proj partials (lifetime: out gemm -> out reduce). Disjoint.
  float*    gpart = (float*)(ws + off);    // 4*512*4096*4 = 8*512*2048*4 = 32 MB

  hipMemsetAsync(ccnt, 0, (size_t)NHEAD * SEQ * 4, stream);
  cache_norm<<<dim3(NHEAD * SCACHE / 4), dim3(256), 0, stream>>>(kcache, kn16, kninv);
  // k/v thirds: split-K=4, 512 blocks; reduce into qkv cols 2048+ (stride 6144)
  gemm_xwT<<<dim3(4 * 32 * 4), dim3(256), 0, stream>>>(hidden, Wqkv + (size_t)2048 * 2048,
                                                       gpart, 2048, 32, 4);
  reduce_k<<<dim3(SEQ * 4096 / 1024), dim3(256), 0, stream>>>(gpart, qkv + 2048, 4, 4096,
                                                              3 * HID);
  // q third, bit-identical chain, 256 blocks
  gemm_q_hi<<<dim3(256), dim3(256), 0, stream>>>(hidden, Wqkv, qkv);
  prep_local<<<dim3(NHEAD * SEQ / 4), dim3(256), 0, stream>>>(qkv, q16, k16, qn16);
  sim_cand<<<dim3(NHEAD * 64), dim3(256), 0, stream>>>(qn16, kn16, ccnt, cidx);
  select_topk<<<dim3(NHEAD * SEQ / 4), dim3(256), 0, stream>>>(ccnt, cidx, qkv, kcache,
                                                               kninv, selidx, selsc);
  attn_part<<<dim3(16 * 80), dim3(256), 0, stream>>>(qkv, q16, k16, bias, pm, pl, po);
  attn_merge<<<dim3(NHEAD * SEQ / 4), dim3(256), 0, stream>>>(pm, pl, po, selidx, selsc,
                                                              vcache, ctx);
  // out-proj: split-K=8, 512 blocks; reduce into d_out
  gemm_xwT<<<dim3(4 * 16 * 8), dim3(256), 0, stream>>>(ctx, Wout, gpart, 2048, 16, 8);
  reduce_k<<<dim3(SEQ * 2048 / 1024), dim3(256), 0, stream>>>(gpart, (float*)d_out, 8, 2048,
                                                              2048);
}

// Round 8
// 456.326 us; speedup vs baseline: 1.6286x; 1.0865x over previous
//
#include <hip/hip_runtime.h>

typedef _Float16 half8 __attribute__((ext_vector_type(8)));
typedef _Float16 half4 __attribute__((ext_vector_type(4)));
typedef _Float16 half2t __attribute__((ext_vector_type(2)));
typedef float f32x4 __attribute__((ext_vector_type(4)));
typedef float f32x2 __attribute__((ext_vector_type(2)));

#define NHEAD 16
#define SEQ 512
#define DIM 128
#define HID 2048
#define SCACHE 8192
#define CAP 64
#define SCALE 0.08838834764831845f   // 1/sqrt(128)
#define NEG_INF (-__builtin_inff())

// ---------------------------------------------------------------------------
// Split-K tile GEMM: Cpart[kblk] = A[M,K] @ B[N,K]^T slice (f16 MFMA).
// 128x128 tiles, BK=64. Smooth outputs only (k/v, out-proj) — q must not.
// ---------------------------------------------------------------------------
__global__ __launch_bounds__(256) void gemm_xwT(const float* __restrict__ A,
                                                const float* __restrict__ B,
                                                float* __restrict__ Cpart,
                                                int K, int gridN, int kslices) {
  __shared__ __align__(16) _Float16 As[128][84];
  __shared__ __align__(16) _Float16 Bs[128][84];
  int b = blockIdx.x;
  int kblk = b % kslices;
  int nm = b / kslices;
  int nblk = nm % gridN, mblk = nm / gridN;
  int N = gridN * 128;
  int kchunk = K / kslices;
  int t = threadIdx.x;
  int lane = t & 63, wid = t >> 6;
  int wm = (wid >> 1) * 64, wn = (wid & 1) * 64;
  f32x4 acc[4][4] = {};
  const float* Ab = A + (size_t)mblk * 128 * K;
  const float* Bb = B + (size_t)nblk * 128 * K;
  int rowS = t >> 4, c4 = (t & 15) * 4;

  for (int k0 = kblk * kchunk; k0 < kblk * kchunk + kchunk; k0 += 64) {
#pragma unroll
    for (int i = 0; i < 8; ++i) {
      int row = rowS + 16 * i;
      float4 av = *(const float4*)(Ab + (size_t)row * K + k0 + c4);
      float4 bv = *(const float4*)(Bb + (size_t)row * K + k0 + c4);
      half4 ah = {(_Float16)av.x, (_Float16)av.y, (_Float16)av.z, (_Float16)av.w};
      half4 bh = {(_Float16)bv.x, (_Float16)bv.y, (_Float16)bv.z, (_Float16)bv.w};
      *(half4*)&As[row][c4] = ah;
      *(half4*)&Bs[row][c4] = bh;
    }
    __syncthreads();
#pragma unroll
    for (int ks = 0; ks < 2; ++ks) {
      int ko = ks * 32 + (lane >> 4) * 8;
      int rr = lane & 15;
      half8 af[4], bf[4];
#pragma unroll
      for (int i = 0; i < 4; ++i) af[i] = *(const half8*)&As[wm + i * 16 + rr][ko];
#pragma unroll
      for (int j = 0; j < 4; ++j) bf[j] = *(const half8*)&Bs[wn + j * 16 + rr][ko];
#pragma unroll
      for (int i = 0; i < 4; ++i)
#pragma unroll
        for (int j = 0; j < 4; ++j)
          acc[i][j] = __builtin_amdgcn_mfma_f32_16x16x32_f16(af[i], bf[j], acc[i][j], 0, 0, 0);
    }
    __syncthreads();
  }
  float* Cp = Cpart + (size_t)kblk * ((size_t)gridN * 128) * 512;
  int cR = (lane >> 4) * 4, cC = lane & 15;
#pragma unroll
  for (int i = 0; i < 4; ++i)
#pragma unroll
    for (int j = 0; j < 4; ++j) {
      int row = mblk * 128 + wm + i * 16 + cR;
      int col = nblk * 128 + wn + j * 16 + cC;
#pragma unroll
      for (int r = 0; r < 4; ++r)
        Cp[(size_t)(row + r) * N + col] = acc[i][j][r];
    }
}

// Deterministic split-K reduce.
__global__ __launch_bounds__(256) void reduce_k(const float* __restrict__ part,
                                                float* __restrict__ dst,
                                                int kslices, int ncol, int dstride) {
  size_t e = ((size_t)blockIdx.x * 256 + threadIdx.x) * 4;
  size_t slice = (size_t)512 * ncol;
  f32x4 s = *(const f32x4*)(part + e);
  for (int p = 1; p < kslices; ++p)
    s += *(const f32x4*)(part + (size_t)p * slice + e);
  size_t row = e / ncol;
  int col = (int)(e % ncol);
  *(f32x4*)(dst + row * dstride + col) = s;
}

// ---------------------------------------------------------------------------
// Streaming fp32 -> (f16 hi, f16 lo) split. Per-element arithmetic IDENTICAL
// to the former in-GEMM conversion (hi=(f16)x, lo=(f16)(x-(float)hi)) —
// q's bits depend on these exact values.
// ---------------------------------------------------------------------------
__global__ __launch_bounds__(256) void split_hilo(const float* __restrict__ src,
                                                  _Float16* __restrict__ hi,
                                                  _Float16* __restrict__ lo) {
  size_t e = ((size_t)blockIdx.x * 256 + threadIdx.x) * 4;
  f32x4 v = *(const f32x4*)(src + e);
  half4 h = {(_Float16)v[0], (_Float16)v[1], (_Float16)v[2], (_Float16)v[3]};
  half4 l = {(_Float16)(v[0] - (float)h[0]), (_Float16)(v[1] - (float)h[1]),
             (_Float16)(v[2] - (float)h[2]), (_Float16)(v[3] - (float)h[3])};
  *(half4*)(hi + e) = h;
  *(half4*)(lo + e) = l;
}

// ---------------------------------------------------------------------------
// q-third at fp32 accuracy via 3-term f16 split MFMA on PRE-SPLIT inputs.
// BIT-IDENTICAL chain per output (K 0..2048 step 32, order lo*hi, hi*lo,
// hi*hi, acc=0). 32x32 tiles -> 1024 blocks (4/CU, 16 waves/CU).
// Writes into qkv cols 0..2047 (stride 6144).
// ---------------------------------------------------------------------------
__global__ __launch_bounds__(256) void gemm_q_hi(const _Float16* __restrict__ Ahg,
                                                 const _Float16* __restrict__ Alg,
                                                 const _Float16* __restrict__ Bhg,
                                                 const _Float16* __restrict__ Blg,
                                                 float* __restrict__ C) {
  __shared__ __align__(16) _Float16 Ahs[32][72], Als[32][72];
  __shared__ __align__(16) _Float16 Bhs[32][72], Bls[32][72];
  int b = blockIdx.x;
  int nblk = b & 63, mblk = b >> 6;   // 64 n-tiles x 16 m-tiles
  int t = threadIdx.x, lane = t & 63, w = t >> 6;
  int wm = (w >> 1) * 16, wn = (w & 1) * 16;
  int quad = lane >> 4, rr = lane & 15;
  f32x4 acc = {};
  const _Float16* Ab0 = Ahg + (size_t)(mblk * 32) * 2048;
  const _Float16* Ab1 = Alg + (size_t)(mblk * 32) * 2048;
  const _Float16* Bb0 = Bhg + (size_t)(nblk * 32) * 2048;
  const _Float16* Bb1 = Blg + (size_t)(nblk * 32) * 2048;
  int srow = t >> 3, sc = (t & 7) * 8;

  for (int k0 = 0; k0 < 2048; k0 += 64) {
    size_t goff = (size_t)srow * 2048 + k0 + sc;
    *(uint4*)&Ahs[srow][sc] = *(const uint4*)(Ab0 + goff);
    *(uint4*)&Als[srow][sc] = *(const uint4*)(Ab1 + goff);
    *(uint4*)&Bhs[srow][sc] = *(const uint4*)(Bb0 + goff);
    *(uint4*)&Bls[srow][sc] = *(const uint4*)(Bb1 + goff);
    __syncthreads();
#pragma unroll
    for (int ks = 0; ks < 2; ++ks) {
      int ko = ks * 32 + quad * 8;
      half8 afh = *(const half8*)&Ahs[wm + rr][ko];
      half8 afl = *(const half8*)&Als[wm + rr][ko];
      half8 bfh = *(const half8*)&Bhs[wn + rr][ko];
      half8 bfl = *(const half8*)&Bls[wn + rr][ko];
      acc = __builtin_amdgcn_mfma_f32_16x16x32_f16(afl, bfh, acc, 0, 0, 0);
      acc = __builtin_amdgcn_mfma_f32_16x16x32_f16(afh, bfl, acc, 0, 0, 0);
      acc = __builtin_amdgcn_mfma_f32_16x16x32_f16(afh, bfh, acc, 0, 0, 0);
    }
    __syncthreads();
  }
  int row = mblk * 32 + wm + quad * 4;
  int col = nblk * 32 + wn + rr;
#pragma unroll
  for (int r = 0; r < 4; ++r)
    C[(size_t)(row + r) * (3 * HID) + col] = acc[r];
}

// ---------------------------------------------------------------------------
// k_cache: f16 normalized copy (filter) + double 1/||k|| (exact re-scoring).
// ---------------------------------------------------------------------------
__global__ __launch_bounds__(256) void cache_norm(const float* __restrict__ kc,
                                                  _Float16* __restrict__ kn16,
                                                  double* __restrict__ kninv) {
  int w = threadIdx.x >> 6, lane = threadIdx.x & 63;
  int row = blockIdx.x * 4 + w;
  f32x2 v = *(const f32x2*)(kc + (size_t)row * DIM + lane * 2);
  double s = (double)v[0] * v[0] + (double)v[1] * v[1];
#pragma unroll
  for (int off = 32; off; off >>= 1) s += __shfl_xor(s, off);
  float inv = rsqrtf((float)s);
  half2t o = {(_Float16)(v[0] * inv), (_Float16)(v[1] * inv)};
  *(half2t*)(kn16 + (size_t)row * DIM + lane * 2) = o;
  if (lane == 0) kninv[row] = 1.0 / sqrt(s);
}

// ---------------------------------------------------------------------------
// From qkv: per-head f16 q, k_local, normalized q. Wave per (h,s).
// ---------------------------------------------------------------------------
__global__ __launch_bounds__(256) void prep_local(const float* __restrict__ qkv,
                                                  _Float16* __restrict__ q16,
                                                  _Float16* __restrict__ k16,
                                                  _Float16* __restrict__ qn16) {
  int w = threadIdx.x >> 6, lane = threadIdx.x & 63;
  int rid = blockIdx.x * 4 + w;
  int h = rid >> 9, s = rid & 511;
  const float* qp = qkv + (size_t)s * (3 * HID) + h * DIM + lane * 2;
  f32x2 q = *(const f32x2*)qp;
  f32x2 k = *(const f32x2*)(qp + HID);
  float ss = q[0] * q[0] + q[1] * q[1];
#pragma unroll
  for (int off = 32; off; off >>= 1) ss += __shfl_xor(ss, off);
  float inv = rsqrtf(ss);
  half2t qh = {(_Float16)q[0], (_Float16)q[1]};
  half2t kh = {(_Float16)k[0], (_Float16)k[1]};
  half2t qnh = {(_Float16)(q[0] * inv), (_Float16)(q[1] * inv)};
  *(half2t*)(q16 + (size_t)rid * DIM + lane * 2) = qh;
  *(half2t*)(k16 + (size_t)rid * DIM + lane * 2) = kh;
  *(half2t*)(qn16 + (size_t)rid * DIM + lane * 2) = qnh;
}

// ---------------------------------------------------------------------------
// Candidate filter: sim = Qn @ Kn^T, f16 MFMA, threshold 0.249 (margin 1e-3).
// K-fragments in registers; Q staged in LDS.
// ---------------------------------------------------------------------------
__global__ __launch_bounds__(256) void sim_cand(const _Float16* __restrict__ qn16,
                                                const _Float16* __restrict__ kn16,
                                                int* __restrict__ cnt,
                                                int* __restrict__ cidx) {
  __shared__ __align__(16) _Float16 Qs[64][132];
  int b = blockIdx.x;
  int h = b & 15, cblk = b >> 4;
  int t = threadIdx.x, lane = t & 63, w = t >> 6;
  int quad = lane >> 4, rr = lane & 15;

  half8 bf[2][4];
  {
    const _Float16* kb = kn16 + ((size_t)(h * SCACHE + cblk * 128 + w * 32)) * DIM;
#pragma unroll
    for (int jn = 0; jn < 2; ++jn)
#pragma unroll
      for (int ks = 0; ks < 4; ++ks)
        bf[jn][ks] = *(const half8*)(kb + (size_t)(jn * 16 + rr) * DIM + ks * 32 + quad * 8);
  }

  for (int qt = 0; qt < 8; ++qt) {
    __syncthreads();
    const _Float16* qb = qn16 + ((size_t)(h * SEQ + qt * 64)) * DIM;
#pragma unroll
    for (int i = 0; i < 4; ++i) {
      int f = t + 256 * i;
      int row = f >> 4, c8 = (f & 15) * 8;
      *(uint4*)&Qs[row][c8] = *(const uint4*)(qb + (size_t)row * DIM + c8);
    }
    __syncthreads();

    f32x4 acc[4][2] = {};
#pragma unroll
    for (int ks = 0; ks < 4; ++ks) {
      int ko = ks * 32 + quad * 8;
      half8 af[4];
#pragma unroll
      for (int i = 0; i < 4; ++i) af[i] = *(const half8*)&Qs[i * 16 + rr][ko];
#pragma unroll
      for (int i = 0; i < 4; ++i)
#pragma unroll
        for (int j = 0; j < 2; ++j)
          acc[i][j] = __builtin_amdgcn_mfma_f32_16x16x32_f16(af[i], bf[j][ks], acc[i][j], 0, 0, 0);
    }
    int qrow_base = qt * 64 + (quad << 2);
    int key_base = cblk * 128 + w * 32 + rr;
#pragma unroll
    for (int i = 0; i < 4; ++i)
#pragma unroll
      for (int j = 0; j < 2; ++j)
#pragma unroll
        for (int r = 0; r < 4; ++r) {
          float v = acc[i][j][r];
          if (v > 0.249f) {
            int q = qrow_base + i * 16 + r;
            int rowid = h * SEQ + q;
            int pos = atomicAdd(&cnt[rowid], 1);
            if (pos < CAP) cidx[rowid * CAP + pos] = key_base + j * 16;
          }
        }
  }
}

// ---------------------------------------------------------------------------
// Candidate-parallel exact re-score + top-16 membership (double precision).
// ---------------------------------------------------------------------------
__global__ __launch_bounds__(256) void select_topk(const int* __restrict__ cnt,
                                                   const int* __restrict__ cidx,
                                                   const float* __restrict__ qkv,
                                                   const float* __restrict__ kcache,
                                                   const double* __restrict__ kninv,
                                                   int* __restrict__ sel_idx,
                                                   float* __restrict__ sel_score) {
  int w = threadIdx.x >> 6, lane = threadIdx.x & 63;
  int rowid = blockIdx.x * 4 + w;
  int h = rowid >> 9, s = rowid & 511;
  const float* qp = qkv + (size_t)s * (3 * HID) + h * DIM;

  f32x2 qv2 = *(const f32x2*)(qp + lane * 2);
  double qs = (double)qv2[0] * qv2[0] + (double)qv2[1] * qv2[1];
#pragma unroll
  for (int off = 32; off; off >>= 1) qs += __shfl_xor(qs, off);
  double thr = 0.25 * sqrt(qs);

  int n = min(cnt[rowid], CAP);
  int idx = 0x7fffffff;
  double r = -1e300, d = 0.0;
  if (lane < n) {
    idx = cidx[rowid * CAP + lane];
    const float* kp = kcache + ((size_t)(h * SCACHE + idx)) * DIM;
    double d0 = 0.0, d1 = 0.0;
#pragma unroll
    for (int j = 0; j < DIM; j += 8) {
      f32x4 ka = *(const f32x4*)(kp + j);
      f32x4 kb = *(const f32x4*)(kp + j + 4);
      f32x4 qa = *(const f32x4*)(qp + j);
      f32x4 qb = *(const f32x4*)(qp + j + 4);
      d0 = fma((double)qa[0], (double)ka[0], d0);
      d1 = fma((double)qa[1], (double)ka[1], d1);
      d0 = fma((double)qa[2], (double)ka[2], d0);
      d1 = fma((double)qa[3], (double)ka[3], d1);
      d0 = fma((double)qb[0], (double)kb[0], d0);
      d1 = fma((double)qb[1], (double)kb[1], d1);
      d0 = fma((double)qb[2], (double)kb[2], d0);
      d1 = fma((double)qb[3], (double)kb[3], d1);
    }
    d = d0 + d1;
    r = d * kninv[h * SCACHE + idx];
  }

  int rank = 0;
  for (int j = 0; j < n; ++j) {
    double rj = __shfl(r, j);
    int ij = __shfl(idx, j);
    if (rj > r || (rj == r && ij < idx)) ++rank;
  }
  bool sel = (lane < n) && (rank < 16) && (r > thr);
  unsigned long long m = __ballot(sel);
  int nsel = __popcll(m);
  if (sel) {
    int pos = __popcll(m & ((1ull << lane) - 1));
    sel_idx[rowid * 16 + pos] = idx;
    sel_score[rowid * 16 + pos] = (float)(d * (double)SCALE);
  }
  if (lane >= nsel && lane < 16) {
    sel_idx[rowid * 16 + lane] = 0;
    sel_score[rowid * 16 + lane] = NEG_INF;
  }
}

// ---------------------------------------------------------------------------
// Flash-style local attention, stage 1.
// ---------------------------------------------------------------------------
__global__ __launch_bounds__(256) void attn_part(const float* __restrict__ qkv,
                                                 const _Float16* __restrict__ q16,
                                                 const _Float16* __restrict__ k16,
                                                 const float* __restrict__ bias,
                                                 float* __restrict__ part_m,
                                                 float* __restrict__ part_l,
                                                 float* __restrict__ part_o) {
  __shared__ __align__(16) _Float16 Vs[128][136];  // V^T: [dim][key]
  __shared__ __align__(16) _Float16 Ps[16][136];   // P:   [q][key]
  __shared__ float mred[16][4], lred[16][4];

  int pb = blockIdx.x;
  int tt = pb % 80, h = pb / 80;
  int qb, cb;
  if (tt < 8)       { qb = tt;                cb = 0; }
  else if (tt < 24) { int u = tt - 8;  qb = 8 + (u >> 1); cb = u & 1; }
  else if (tt < 48) { int u = tt - 24; int q3 = u / 3; qb = 16 + q3; cb = u - q3 * 3; }
  else              { int u = tt - 48; qb = 24 + (u >> 2); cb = u & 3; }
  int q0 = qb * 16, kc0 = cb * 128;

  int t = threadIdx.x, lane = t & 63, w = t >> 6;
  int quad = lane >> 4, col = lane & 15;

  const float* vbase = qkv + 2 * HID + h * DIM;
#pragma unroll
  for (int i = 0; i < 16; ++i) {
    int idx = t + 256 * i;
    int key = idx & 127, dg = idx >> 7;
    f32x4 vv = *(const f32x4*)(vbase + (size_t)(kc0 + key) * (3 * HID) + dg * 4);
#pragma unroll
    for (int e = 0; e < 4; ++e) Vs[dg * 4 + e][key] = (_Float16)vv[e];
  }

  const _Float16* qbp = q16 + ((size_t)(h * SEQ + q0)) * DIM;
  half8 af[4];
#pragma unroll
  for (int ks = 0; ks < 4; ++ks)
    af[ks] = *(const half8*)(qbp + (size_t)col * DIM + ks * 32 + quad * 8);

  f32x4 acc[2] = {};
#pragma unroll
  for (int jn = 0; jn < 2; ++jn) {
    const _Float16* kp = k16 + ((size_t)(h * SEQ + kc0 + w * 32 + jn * 16 + col)) * DIM;
#pragma unroll
    for (int ks = 0; ks < 4; ++ks) {
      half8 bf = *(const half8*)(kp + ks * 32 + quad * 8);
      acc[jn] = __builtin_amdgcn_mfma_f32_16x16x32_f16(af[ks], bf, acc[jn], 0, 0, 0);
    }
  }
  float s[2][4];
#pragma unroll
  for (int jn = 0; jn < 2; ++jn) {
    int keyg = kc0 + w * 32 + jn * 16 + col;
#pragma unroll
    for (int r = 0; r < 4; ++r) {
      int qrow = q0 + quad * 4 + r;
      float sv = NEG_INF;
      if (keyg <= qrow)
        sv = acc[jn][r] * SCALE + bias[((size_t)h * SEQ + qrow) * SEQ + keyg];
      s[jn][r] = sv;
    }
  }

  float mw[4];
#pragma unroll
  for (int r = 0; r < 4; ++r) {
    float m = fmaxf(s[0][r], s[1][r]);
#pragma unroll
    for (int off = 1; off < 16; off <<= 1) m = fmaxf(m, __shfl_xor(m, off));
    mw[r] = m;
  }
  if (col == 0)
#pragma unroll
    for (int r = 0; r < 4; ++r) mred[quad * 4 + r][w] = mw[r];
  __syncthreads();

  float M[4];
#pragma unroll
  for (int r = 0; r < 4; ++r) {
    int row = quad * 4 + r;
    float m = fmaxf(fmaxf(mred[row][0], mred[row][1]),
                    fmaxf(mred[row][2], mred[row][3]));
    M[r] = m;
    float p0 = __expf(s[0][r] - m);
    float p1 = __expf(s[1][r] - m);
    Ps[row][w * 32 + col] = (_Float16)p0;
    Ps[row][w * 32 + 16 + col] = (_Float16)p1;
    float l = p0 + p1;
#pragma unroll
    for (int off = 1; off < 16; off <<= 1) l += __shfl_xor(l, off);
    if (col == 0) lred[row][w] = l;
  }
  if (w == 0 && col == 0)
#pragma unroll
    for (int r = 0; r < 4; ++r) part_m[pb * 16 + quad * 4 + r] = M[r];
  __syncthreads();

  f32x4 o[2] = {};
#pragma unroll
  for (int jn = 0; jn < 2; ++jn) {
#pragma unroll
    for (int ks = 0; ks < 4; ++ks) {
      half8 a = *(const half8*)&Ps[col][ks * 32 + quad * 8];
      half8 bv = *(const half8*)&Vs[w * 32 + jn * 16 + col][ks * 32 + quad * 8];
      o[jn] = __builtin_amdgcn_mfma_f32_16x16x32_f16(a, bv, o[jn], 0, 0, 0);
    }
  }
#pragma unroll
  for (int jn = 0; jn < 2; ++jn)
#pragma unroll
    for (int r = 0; r < 4; ++r)
      part_o[((size_t)pb * 16 + quad * 4 + r) * 128 + w * 32 + jn * 16 + col] = o[jn][r];
  if (t < 16)
    part_l[pb * 16 + t] = lred[t][0] + lred[t][1] + lred[t][2] + lred[t][3];
}

// ---------------------------------------------------------------------------
// Flash merge: wave per (h,q) row.
// ---------------------------------------------------------------------------
__global__ __launch_bounds__(256) void attn_merge(const float* __restrict__ part_m,
                                                  const float* __restrict__ part_l,
                                                  const float* __restrict__ part_o,
                                                  const int* __restrict__ sel_idx,
                                                  const float* __restrict__ sel_score,
                                                  const float* __restrict__ vcache,
                                                  float* __restrict__ ctx) {
  int w = threadIdx.x >> 6, lane = threadIdx.x & 63;
  int row = blockIdx.x * 4 + w;
  int h = row >> 9, q = row & 511;
  int qb = q >> 4, r = q & 15;
  int base = (qb < 8) ? qb
           : (qb < 16) ? 8 + 2 * (qb - 8)
           : (qb < 24) ? 24 + 3 * (qb - 16)
                       : 48 + 4 * (qb - 24);
  int ncb = (qb >> 3) + 1;
  int pb0 = h * 80 + base;

  float scv[16], mc = NEG_INF;
#pragma unroll
  for (int j = 0; j < 16; ++j) {
    scv[j] = sel_score[row * 16 + j];
    mc = fmaxf(mc, scv[j]);
  }
  float mi[4];
  float M = mc;
  for (int i = 0; i < ncb; ++i) {
    mi[i] = part_m[(pb0 + i) * 16 + r];
    M = fmaxf(M, mi[i]);
  }
  f32x2 O = {0.f, 0.f};
  float L = 0.f;
  for (int i = 0; i < ncb; ++i) {
    float sc = __expf(mi[i] - M);
    f32x2 ov = *(const f32x2*)(part_o + ((size_t)(pb0 + i) * 16 + r) * 128 + lane * 2);
    O += ov * sc;
    L += part_l[(pb0 + i) * 16 + r] * sc;
  }
#pragma unroll
  for (int j = 0; j < 16; ++j) {
    if (scv[j] > NEG_INF) {
      float wv = __expf(scv[j] - M);
      int idx = sel_idx[row * 16 + j];
      f32x2 v = *(const f32x2*)(vcache + ((size_t)(h * SCACHE + idx)) * DIM + lane * 2);
      O += v * wv;
      L += wv;
    }
  }
  f32x2 res = O * (1.f / L);
  *(f32x2*)(ctx + (size_t)q * HID + h * DIM + lane * 2) = res;
}

// ---------------------------------------------------------------------------
extern "C" void kernel_launch(void* const* d_in, const int* in_sizes, int n_in,
                              void* d_out, int out_size, void* d_ws, size_t ws_size,
                              hipStream_t stream) {
  const float* hidden = (const float*)d_in[0];
  const float* Wqkv   = (const float*)d_in[1];
  const float* Wout   = (const float*)d_in[2];
  const float* kcache = (const float*)d_in[3];
  const float* vcache = (const float*)d_in[4];
  const float* bias   = (const float*)d_in[5];

  char* ws = (char*)d_ws;
  size_t off = 0;
  float*    qkv   = (float*)(ws + off);    off += (size_t)SEQ * 3 * HID * 4;
  _Float16* q16   = (_Float16*)(ws + off); off += (size_t)NHEAD * SEQ * DIM * 2;
  _Float16* k16   = (_Float16*)(ws + off); off += (size_t)NHEAD * SEQ * DIM * 2;
  _Float16* qn16  = (_Float16*)(ws + off); off += (size_t)NHEAD * SEQ * DIM * 2;
  _Float16* kn16  = (_Float16*)(ws + off); off += (size_t)NHEAD * SCACHE * DIM * 2;
  double*   kninv = (double*)(ws + off);   off += (size_t)NHEAD * SCACHE * 8;
  int*      ccnt  = (int*)(ws + off);      off += (size_t)NHEAD * SEQ * 4;
  int*      cidx  = (int*)(ws + off);      off += (size_t)NHEAD * SEQ * CAP * 4;
  int*      selidx  = (int*)(ws + off);    off += (size_t)NHEAD * SEQ * 16 * 4;
  float*    selsc   = (float*)(ws + off);  off += (size_t)NHEAD * SEQ * 16 * 4;
  float*    ctx   = (float*)(ws + off);    off += (size_t)SEQ * HID * 4;
  float*    pm    = (float*)(ws + off);    off += (size_t)1280 * 16 * 4;
  float*    pl    = (float*)(ws + off);    off += (size_t)1280 * 16 * 4;
  float*    po    = (float*)(ws + off);    off += (size_t)1280 * 16 * 128 * 4;
  // 32 MB union region, three disjoint lifetimes on the serial stream:
  //  (1) kv split-K partials   (kv gemm -> kv reduce)
  //  (2) q hi/lo f16 buffers   (split_hilo -> gemm_q_hi)   [20 MB]
  //  (3) out-proj partials     (out gemm -> out reduce)
  float*    gpart = (float*)(ws + off);
  _Float16* Ahg = (_Float16*)gpart;                       // 512*2048 f16 = 2 MB
  _Float16* Alg = Ahg + (size_t)SEQ * HID;
  _Float16* Bhg = Alg + (size_t)SEQ * HID;                // 2048*2048 f16 = 8 MB
  _Float16* Blg = Bhg + (size_t)HID * HID;

  hipMemsetAsync(ccnt, 0, (size_t)NHEAD * SEQ * 4, stream);
  cache_norm<<<dim3(NHEAD * SCACHE / 4), dim3(256), 0, stream>>>(kcache, kn16, kninv);
  // k/v thirds: split-K=4, 512 blocks; reduce into qkv cols 2048+ (stride 6144)
  gemm_xwT<<<dim3(4 * 32 * 4), dim3(256), 0, stream>>>(hidden, Wqkv + (size_t)2048 * 2048,
                                                       gpart, 2048, 32, 4);
  reduce_k<<<dim3(SEQ * 4096 / 1024), dim3(256), 0, stream>>>(gpart, qkv + 2048, 4, 4096,
                                                              3 * HID);
  // q third: pre-split hi/lo, then bit-identical 3-term chain, 1024 blocks
  split_hilo<<<dim3(SEQ * HID / 1024), dim3(256), 0, stream>>>(hidden, Ahg, Alg);
  split_hilo<<<dim3(HID * HID / 1024), dim3(256), 0, stream>>>(Wqkv, Bhg, Blg);
  gemm_q_hi<<<dim3(1024), dim3(256), 0, stream>>>(Ahg, Alg, Bhg, Blg, qkv);
  prep_local<<<dim3(NHEAD * SEQ / 4), dim3(256), 0, stream>>>(qkv, q16, k16, qn16);
  sim_cand<<<dim3(NHEAD * 64), dim3(256), 0, stream>>>(qn16, kn16, ccnt, cidx);
  select_topk<<<dim3(NHEAD * SEQ / 4), dim3(256), 0, stream>>>(ccnt, cidx, qkv, kcache,
                                                               kninv, selidx, selsc);
  attn_part<<<dim3(16 * 80), dim3(256), 0, stream>>>(qkv, q16, k16, bias, pm, pl, po);
  attn_merge<<<dim3(NHEAD * SEQ / 4), dim3(256), 0, stream>>>(pm, pl, po, selidx, selsc,
                                                              vcache, ctx);
  // out-proj: split-K=8, 512 blocks; reduce into d_out
  gemm_xwT<<<dim3(4 * 16 * 8), dim3(256), 0, stream>>>(ctx, Wout, gpart, 2048, 16, 8);
  reduce_k<<<dim3(SEQ * 2048 / 1024), dim3(256), 0, stream>>>(gpart, (float*)d_out, 8, 2048,
                                                              2048);
}